// Round 4
// baseline (15084.663 us; speedup 1.0000x reference)
//
#include <hip/hip_runtime.h>
#include <math.h>

// Problem constants
#define BB   64
#define NN   1024
#define DIN  16
#define DD   256
#define HH   4
#define LL   3
#define DHH  64
#define DFF2 1024
#define KSEL 64

// ---------------------------------------------------------------------------
// Embedding: h[row, :] = x[row, :16] @ emb_W + emb_b.  4 rows per block.
// ---------------------------------------------------------------------------
__global__ __launch_bounds__(256) void embed_kernel(
    const float* __restrict__ x, const float* __restrict__ W,
    const float* __restrict__ bias, float* __restrict__ h)
{
  __shared__ float xs[4][DIN];
  const int t = threadIdx.x, w = t >> 6, lane = t & 63;
  const size_t row = (size_t)blockIdx.x * 4 + w;
  if (lane < DIN) xs[w][lane] = x[row * DIN + lane];
  __syncthreads();
#pragma unroll
  for (int j = 0; j < 4; ++j) {
    const int col = lane + j * 64;
    float acc = bias[col];
#pragma unroll
    for (int kk = 0; kk < DIN; ++kk) acc = fmaf(xs[w][kk], W[kk * DD + col], acc);
    h[row * DD + col] = acc;
  }
}

// ---------------------------------------------------------------------------
// fp32 GEMM: C[M,N] = A[M,K] @ B[K,N] (+bias)(+res)(relu)(accum)
// 128x128 tile, BK=16, DOUBLE-BUFFERED LDS (1 barrier / 16 k-steps),
// 256 threads, 8x8 micro-tile.  Global loads for tile t+1 issued before
// computing tile t (latency hidden under 1024 FMAs).
// B column-quads rotate-interleaved (phys = (cq>>1)|((cq&1)<<4)) -> 2-way reads.
// ---------------------------------------------------------------------------
__global__ __launch_bounds__(256) void gemm128_kernel(
    const float* __restrict__ A, int lda,
    const float* __restrict__ Bm, int ldb,
    float* C, int ldc,
    const float* __restrict__ bias,
    const float* res, int ldres,
    int Kk, int relu, int accum)
{
  __shared__ __align__(16) float As[2][16][132];
  __shared__ __align__(16) float Bs[2][16][132];
  const int t = threadIdx.x;
  const int tx = t & 15, ty = t >> 4;
  const size_t row0 = (size_t)blockIdx.y * 128;
  const size_t col0 = (size_t)blockIdx.x * 128;
  // A loader: row = t>>1 (128 rows x 2 threads), k-half = (t&1)*8
  const int arow = t >> 1, ak = (t & 1) * 8;
  // B loader: k-row = t>>4 (16), col-quad = t&15 (plus +16 partner)
  const int brow = t >> 4, bcq = t & 15;
  const int bp = ((bcq >> 1) | ((bcq & 1) << 4)) * 4;  // phys float offset
  const float* Aptr = A + (row0 + arow) * lda + ak;
  const float* Bptr = Bm + (size_t)brow * ldb + col0 + bcq * 4;

  float4 a0r, a1r, b0r, b1r;
  a0r = *(const float4*)(Aptr);
  a1r = *(const float4*)(Aptr + 4);
  b0r = *(const float4*)(Bptr);
  b1r = *(const float4*)(Bptr + 64);
  {
    As[0][ak + 0][arow] = a0r.x; As[0][ak + 1][arow] = a0r.y;
    As[0][ak + 2][arow] = a0r.z; As[0][ak + 3][arow] = a0r.w;
    As[0][ak + 4][arow] = a1r.x; As[0][ak + 5][arow] = a1r.y;
    As[0][ak + 6][arow] = a1r.z; As[0][ak + 7][arow] = a1r.w;
    *(float4*)&Bs[0][brow][bp] = b0r;
    *(float4*)&Bs[0][brow][bp + 32] = b1r;
  }
  __syncthreads();

  float acc[8][8] = {};
  const int NT = Kk >> 4;
  for (int kt = 0; kt < NT; ++kt) {
    const int cur = kt & 1;
    if (kt + 1 < NT) {
      const int k0 = (kt + 1) * 16;
      a0r = *(const float4*)(Aptr + k0);
      a1r = *(const float4*)(Aptr + k0 + 4);
      b0r = *(const float4*)(Bptr + (size_t)k0 * ldb);
      b1r = *(const float4*)(Bptr + (size_t)k0 * ldb + 64);
    }
#pragma unroll
    for (int kk = 0; kk < 16; ++kk) {
      const float4 x0 = *(const float4*)&As[cur][kk][ty * 8];
      const float4 x1 = *(const float4*)&As[cur][kk][ty * 8 + 4];
      const float4 y0 = *(const float4*)&Bs[cur][kk][tx * 4];
      const float4 y1 = *(const float4*)&Bs[cur][kk][tx * 4 + 64];
      const float aa[8] = {x0.x, x0.y, x0.z, x0.w, x1.x, x1.y, x1.z, x1.w};
      const float bb2[8] = {y0.x, y0.y, y0.z, y0.w, y1.x, y1.y, y1.z, y1.w};
#pragma unroll
      for (int i = 0; i < 8; ++i)
#pragma unroll
        for (int j = 0; j < 8; ++j)
          acc[i][j] = fmaf(aa[i], bb2[j], acc[i][j]);
    }
    if (kt + 1 < NT) {
      const int nxt = cur ^ 1;
      As[nxt][ak + 0][arow] = a0r.x; As[nxt][ak + 1][arow] = a0r.y;
      As[nxt][ak + 2][arow] = a0r.z; As[nxt][ak + 3][arow] = a0r.w;
      As[nxt][ak + 4][arow] = a1r.x; As[nxt][ak + 5][arow] = a1r.y;
      As[nxt][ak + 6][arow] = a1r.z; As[nxt][ak + 7][arow] = a1r.w;
      *(float4*)&Bs[nxt][brow][bp] = b0r;
      *(float4*)&Bs[nxt][brow][bp + 32] = b1r;
    }
    __syncthreads();
  }
#pragma unroll
  for (int i = 0; i < 8; ++i) {
    const size_t r = row0 + ty * 8 + i;
    float* cp = C + r * (size_t)ldc + col0 + tx * 8;
    const float* rp = res ? res + r * (size_t)ldres + col0 + tx * 8 : nullptr;
#pragma unroll
    for (int j = 0; j < 8; ++j) {
      const size_t c = col0 + tx * 8 + j;
      float v = acc[i][j];
      if (bias) v += bias[c];
      if (rp)   v += rp[j];
      if (relu) v = fmaxf(v, 0.f);
      if (accum) v += cp[j];
      cp[j] = v;
    }
  }
}

// ---------------------------------------------------------------------------
// Flash attention v4, fp32.  One block = one (b, head, 128-row q-tile).
// 8x4 micro-tiles: QK = 12 LDS reads per 128 FMA, PV likewise (10.7 FMA/read
// vs 8 before -> attacks the measured LDS-throughput bound).
// LDS: Qn[128x64] 32K | KV[64x64] 16K (K/V time-shared) | Pt[64x128] 32K
//      = 81920 B exactly -> 2 blocks/CU.
// All tiles XOR-quad swizzled: phys_quad = cq ^ ((row>>2)&15)  (<=2-way).
// K_{t+1}/V_t prefetched into regs under compute; 4 barriers per k-tile
// (half per unit work vs v3).
// ---------------------------------------------------------------------------
#define TFQ(r, cq) ((r) * 64 + 4 * ((((r) >> 2) ^ (cq)) & 15))
#define TFP(r, cq) ((r) * 128 + 4 * (((((r) >> 2) & 15) ^ (cq)) & 31))

__global__ __launch_bounds__(256) void attn_kernel(
    const float* __restrict__ qb, const float* __restrict__ kb,
    const float* __restrict__ vb, float* __restrict__ ob)
{
  __shared__ __align__(16) float Qn[128 * 64];
  __shared__ __align__(16) float KV[64 * 64];
  __shared__ __align__(16) float Pt[64 * 128];
  const int t = threadIdx.x;
  const int tx = t & 15, ty = t >> 4;
  const int qt = blockIdx.x, hh = blockIdx.y, b = blockIdx.z;
  const size_t base = ((size_t)b * NN) * DD + (size_t)hh * DHH;
  const int srow = t >> 4, scq = t & 15;

  // ---- stage Q (128 rows) and K0; prefetch V0 into regs ----
  {
    const float* qp = qb + base + (size_t)(qt * 128) * DD + scq * 4;
#pragma unroll
    for (int u = 0; u < 8; ++u) {
      const int r = srow + 16 * u;
      *(float4*)&Qn[TFQ(r, scq)] = *(const float4*)(qp + (size_t)r * DD);
    }
    const float* kp = kb + base + scq * 4;
#pragma unroll
    for (int u = 0; u < 4; ++u) {
      const int r = srow + 16 * u;
      *(float4*)&KV[TFQ(r, scq)] = *(const float4*)(kp + (size_t)r * DD);
    }
  }
  float4 vreg[4];
  {
    const float* vp = vb + base + scq * 4;
#pragma unroll
    for (int u = 0; u < 4; ++u)
      vreg[u] = *(const float4*)(vp + (size_t)(srow + 16 * u) * DD);
  }
  __syncthreads();

  // row-base pointers (static-indexed in unrolled loops -> stay in regs)
  const float* qrow[8];
  const float* krow[4];
#pragma unroll
  for (int ii = 0; ii < 4; ++ii) {
    qrow[ii]     = &Qn[(4 * ty + ii) * 64];
    qrow[4 + ii] = &Qn[(64 + 4 * ty + ii) * 64];
    krow[ii]     = &KV[(4 * tx + ii) * 64];
  }

  float O[8][4] = {}, mrun[8], lrun[8] = {};
#pragma unroll
  for (int i = 0; i < 8; ++i) mrun[i] = -1e30f;

  for (int kt = 0; kt < 16; ++kt) {
    // ---- S = Q K^T (8x4 micro) ----
    float S[8][4] = {};
#pragma unroll
    for (int dq = 0; dq < 16; ++dq) {
      const int xq = 4 * ((dq ^ ty) & 15);
      const int xk = 4 * ((dq ^ tx) & 15);
      float4 k4[4];
#pragma unroll
      for (int jj = 0; jj < 4; ++jj) k4[jj] = *(const float4*)(krow[jj] + xk);
#pragma unroll
      for (int ii = 0; ii < 8; ++ii) {
        const float4 q4 = *(const float4*)(qrow[ii] + xq);
#pragma unroll
        for (int jj = 0; jj < 4; ++jj)
          S[ii][jj] += q4.x * k4[jj].x + q4.y * k4[jj].y +
                       q4.z * k4[jj].z + q4.w * k4[jj].w;
      }
    }

    // prefetch K_{kt+1} (consumed after bar C)
    float4 kreg[4];
    {
      const float* kp = kb + base + (size_t)(((kt + 1) & 15) * 64) * DD + scq * 4;
#pragma unroll
      for (int u = 0; u < 4; ++u)
        kreg[u] = *(const float4*)(kp + (size_t)(srow + 16 * u) * DD);
    }

    // ---- online softmax (8 rows; 16-lane tx-groups share a row) ----
    float alpha[8];
#pragma unroll
    for (int ii = 0; ii < 8; ++ii) {
      float mt = -1e30f;
#pragma unroll
      for (int jj = 0; jj < 4; ++jj) { S[ii][jj] *= 0.125f; mt = fmaxf(mt, S[ii][jj]); }
#pragma unroll
      for (int off = 1; off < 16; off <<= 1) mt = fmaxf(mt, __shfl_xor(mt, off));
      const float mnew = fmaxf(mrun[ii], mt);
      alpha[ii] = __expf(mrun[ii] - mnew);
      mrun[ii] = mnew;
      float rs = 0.f;
#pragma unroll
      for (int jj = 0; jj < 4; ++jj) { S[ii][jj] = __expf(S[ii][jj] - mnew); rs += S[ii][jj]; }
#pragma unroll
      for (int off = 1; off < 16; off <<= 1) rs += __shfl_xor(rs, off);
      lrun[ii] = lrun[ii] * alpha[ii] + rs;
    }

    __syncthreads();  // bar A: QK done reading KV(K); prev PV done with Pt

    // V regs -> KV; P^T -> Pt
#pragma unroll
    for (int u = 0; u < 4; ++u)
      *(float4*)&KV[TFQ(srow + 16 * u, scq)] = vreg[u];
#pragma unroll
    for (int jj = 0; jj < 4; ++jj) {
      const float4 plo = {S[0][jj], S[1][jj], S[2][jj], S[3][jj]};
      const float4 phi = {S[4][jj], S[5][jj], S[6][jj], S[7][jj]};
      *(float4*)&Pt[TFP(4 * tx + jj, ty)] = plo;
      *(float4*)&Pt[TFP(4 * tx + jj, 16 + ty)] = phi;
    }

    __syncthreads();  // bar B: V, Pt visible

    // prefetch V_{kt+1} (consumed at next iter's bar A)
    {
      const float* vp = vb + base + (size_t)(((kt + 1) & 15) * 64) * DD + scq * 4;
#pragma unroll
      for (int u = 0; u < 4; ++u)
        vreg[u] = *(const float4*)(vp + (size_t)(srow + 16 * u) * DD);
    }

    // ---- O = O*alpha + P V ----
#pragma unroll
    for (int ii = 0; ii < 8; ++ii)
#pragma unroll
      for (int jj = 0; jj < 4; ++jj) O[ii][jj] *= alpha[ii];
#pragma unroll 16
    for (int c = 0; c < 64; ++c) {
      const int sc = (c >> 2) & 15;
      const float4 plo = *(const float4*)&Pt[c * 128 + 4 * (ty ^ sc)];
      const float4 phi = *(const float4*)&Pt[c * 128 + 4 * ((16 + ty) ^ sc)];
      const float4 v4  = *(const float4*)&KV[c * 64 + 4 * (tx ^ sc)];
      const float pl[4] = {plo.x, plo.y, plo.z, plo.w};
      const float ph[4] = {phi.x, phi.y, phi.z, phi.w};
#pragma unroll
      for (int ii = 0; ii < 4; ++ii) {
        O[ii][0] = fmaf(pl[ii], v4.x, O[ii][0]);
        O[ii][1] = fmaf(pl[ii], v4.y, O[ii][1]);
        O[ii][2] = fmaf(pl[ii], v4.z, O[ii][2]);
        O[ii][3] = fmaf(pl[ii], v4.w, O[ii][3]);
        O[4 + ii][0] = fmaf(ph[ii], v4.x, O[4 + ii][0]);
        O[4 + ii][1] = fmaf(ph[ii], v4.y, O[4 + ii][1]);
        O[4 + ii][2] = fmaf(ph[ii], v4.z, O[4 + ii][2]);
        O[4 + ii][3] = fmaf(ph[ii], v4.w, O[4 + ii][3]);
      }
    }

    __syncthreads();  // bar C: PV done reading KV(V)

    // K regs -> KV (for next iteration)
#pragma unroll
    for (int u = 0; u < 4; ++u)
      *(float4*)&KV[TFQ(srow + 16 * u, scq)] = kreg[u];

    __syncthreads();  // bar D: K visible
  }

  // ---- write O ----
#pragma unroll
  for (int ii = 0; ii < 8; ++ii) {
    const int r = (ii < 4) ? (4 * ty + ii) : (64 + 4 * ty + (ii - 4));
    const float inv = 1.f / lrun[ii];
    const float4 o4 = {O[ii][0] * inv, O[ii][1] * inv, O[ii][2] * inv, O[ii][3] * inv};
    *(float4*)(ob + base + (size_t)(qt * 128 + r) * DD + 4 * tx) = o4;
  }
}

// ---------------------------------------------------------------------------
// LayerNorm over D=256, 4 rows/block (one wave per row, shfl reduce).
// ---------------------------------------------------------------------------
__global__ __launch_bounds__(256) void ln_kernel(
    const float* in, float* out,
    const float* __restrict__ g, const float* __restrict__ bb)
{
  const int t = threadIdx.x, w = t >> 6, lane = t & 63;
  const size_t row = (size_t)blockIdx.x * 4 + w;
  const float4 val = *(const float4*)(in + row * DD + lane * 4);
  float s = val.x + val.y + val.z + val.w;
#pragma unroll
  for (int off = 32; off; off >>= 1) s += __shfl_xor(s, off);
  const float mean = s * (1.f / 256.f);
  const float dx = val.x - mean, dy = val.y - mean, dz = val.z - mean, dw = val.w - mean;
  float ss = dx * dx + dy * dy + dz * dz + dw * dw;
#pragma unroll
  for (int off = 32; off; off >>= 1) ss += __shfl_xor(ss, off);
  const float inv = rsqrtf(ss * (1.f / 256.f) + 1e-5f);
  const float4 g4 = *(const float4*)(g + lane * 4);
  const float4 b4 = *(const float4*)(bb + lane * 4);
  float4 o4;
  o4.x = dx * inv * g4.x + b4.x;
  o4.y = dy * inv * g4.y + b4.y;
  o4.z = dz * inv * g4.z + b4.z;
  o4.w = dw * inv * g4.w + b4.w;
  *(float4*)(out + row * DD + lane * 4) = o4;
}

// ---------------------------------------------------------------------------
// h_mean[b, :] = mean over N of h[b, :, :]
// ---------------------------------------------------------------------------
__global__ __launch_bounds__(256) void rowmean_kernel(
    const float* __restrict__ h, float* __restrict__ hm)
{
  const int t = threadIdx.x, b = blockIdx.x;
  const float* p = h + (size_t)b * NN * DD + t;
  float acc = 0.f;
  for (int n = 0; n < NN; ++n) acc += p[(size_t)n * DD];
  hm[b * DD + t] = acc * (1.f / NN);
}

// ---------------------------------------------------------------------------
// Per-batch small heads: qv = h_mean@sha_Wq; alloc = softmax(relu(h_mean@W1+b1)@W2+b2)
// ---------------------------------------------------------------------------
__global__ __launch_bounds__(256) void final_small_kernel(
    const float* __restrict__ hm, const float* __restrict__ shaWq,
    const float* __restrict__ W1, const float* __restrict__ b1,
    const float* __restrict__ W2, const float* __restrict__ b2,
    float* __restrict__ qv, float* __restrict__ allocp)
{
  __shared__ float hs[256];
  __shared__ float mids[256];
  __shared__ float red[256];
  const int t = threadIdx.x, b = blockIdx.x;
  hs[t] = hm[b * 256 + t];
  __syncthreads();
  float a = 0.f, m2 = b1[t];
  for (int kk = 0; kk < 256; ++kk) {
    const float hv = hs[kk];
    a  = fmaf(hv, shaWq[kk * 256 + t], a);
    m2 = fmaf(hv, W1[kk * 256 + t], m2);
  }
  qv[b * 256 + t] = a;
  mids[t] = fmaxf(m2, 0.f);
  __syncthreads();
  float lg[4];
#pragma unroll
  for (int j = 0; j < 4; ++j) {
    const int n = t + j * 256;
    float acc2 = b2[n];
    for (int kk = 0; kk < 256; ++kk) acc2 = fmaf(mids[kk], W2[kk * 1024 + n], acc2);
    lg[j] = acc2;
  }
  float m = fmaxf(fmaxf(lg[0], lg[1]), fmaxf(lg[2], lg[3]));
  red[t] = m; __syncthreads();
  for (int s2 = 128; s2; s2 >>= 1) { if (t < s2) red[t] = fmaxf(red[t], red[t + s2]); __syncthreads(); }
  m = red[0]; __syncthreads();
  float e[4]; float ls = 0.f;
#pragma unroll
  for (int j = 0; j < 4; ++j) { e[j] = expf(lg[j] - m); ls += e[j]; }
  red[t] = ls; __syncthreads();
  for (int s2 = 128; s2; s2 >>= 1) { if (t < s2) red[t] += red[t + s2]; __syncthreads(); }
  const float invs = 1.f / red[0];
#pragma unroll
  for (int j = 0; j < 4; ++j) allocp[(size_t)b * 1024 + t + j * 256] = e[j] * invs;
}

// ---------------------------------------------------------------------------
// scores[b,n] = dot(qv[b], kv[b,n])/16; weights = softmax((scores+g)/0.5)
// ---------------------------------------------------------------------------
__global__ __launch_bounds__(256) void scores_kernel(
    const float* __restrict__ qv, const float* __restrict__ kv,
    const float* __restrict__ gum, float* __restrict__ outW,
    float* __restrict__ wcopy)
{
  __shared__ __align__(16) float qs[256];
  __shared__ float sc[1024];
  __shared__ float red[256];
  const int t = threadIdx.x, b = blockIdx.x;
  const int w = t >> 6, lane = t & 63;
  qs[t] = qv[b * 256 + t];
  __syncthreads();
  const float4 myq = *(const float4*)&qs[lane * 4];
  for (int n = w; n < 1024; n += 4) {
    const float4 k4 = *(const float4*)(kv + ((size_t)b * 1024 + n) * 256 + lane * 4);
    float d = myq.x * k4.x + myq.y * k4.y + myq.z * k4.z + myq.w * k4.w;
#pragma unroll
    for (int off = 32; off; off >>= 1) d += __shfl_xor(d, off);
    if (lane == 0) sc[n] = d * (1.f / 16.f);
  }
  __syncthreads();
  float z[4];
#pragma unroll
  for (int j = 0; j < 4; ++j) {
    const int n = t + j * 256;
    z[j] = (sc[n] + gum[(size_t)b * 1024 + n]) * 2.0f;  // /TAU, TAU=0.5
  }
  float m = fmaxf(fmaxf(z[0], z[1]), fmaxf(z[2], z[3]));
  red[t] = m; __syncthreads();
  for (int s2 = 128; s2; s2 >>= 1) { if (t < s2) red[t] = fmaxf(red[t], red[t + s2]); __syncthreads(); }
  m = red[0]; __syncthreads();
  float e[4]; float ls = 0.f;
#pragma unroll
  for (int j = 0; j < 4; ++j) { e[j] = expf(z[j] - m); ls += e[j]; }
  red[t] = ls; __syncthreads();
  for (int s2 = 128; s2; s2 >>= 1) { if (t < s2) red[t] += red[t + s2]; __syncthreads(); }
  const float invs = 1.f / red[0];
#pragma unroll
  for (int j = 0; j < 4; ++j) {
    const int n = t + j * 256;
    const float wv = e[j] * invs;
    outW[(size_t)b * 1024 + n] = wv;
    wcopy[(size_t)b * 1024 + n] = wv;
  }
}

// ---------------------------------------------------------------------------
// Top-64 (descending, ties -> lower index, matching jax.lax.top_k) + sel gather.
// ---------------------------------------------------------------------------
__global__ __launch_bounds__(256) void topk_kernel(
    const float* __restrict__ wcopy, const float* __restrict__ allocp,
    float* __restrict__ outI, float* __restrict__ outS)
{
  __shared__ float wv[1024];
  __shared__ float rv[4];
  __shared__ int   ri[4];
  __shared__ int   sel[64];
  const int t = threadIdx.x, b = blockIdx.x;
  const int w = t >> 6, lane = t & 63;
#pragma unroll
  for (int j = 0; j < 4; ++j) wv[t * 4 + j] = wcopy[(size_t)b * 1024 + t * 4 + j];
  __syncthreads();
  for (int it = 0; it < 64; ++it) {
    float bv = -1.f; int bi = 1 << 20;
#pragma unroll
    for (int j = 0; j < 4; ++j) {
      const int n = t * 4 + j;
      const float v2 = wv[n];
      if (v2 > bv || (v2 == bv && n < bi)) { bv = v2; bi = n; }
    }
#pragma unroll
    for (int off = 32; off; off >>= 1) {
      const float ov = __shfl_xor(bv, off);
      const int   oi = __shfl_xor(bi, off);
      if (ov > bv || (ov == bv && oi < bi)) { bv = ov; bi = oi; }
    }
    if (lane == 0) { rv[w] = bv; ri[w] = bi; }
    __syncthreads();
    if (t == 0) {
      float B2 = rv[0]; int I2 = ri[0];
      for (int u = 1; u < 4; ++u)
        if (rv[u] > B2 || (rv[u] == B2 && ri[u] < I2)) { B2 = rv[u]; I2 = ri[u]; }
      sel[it] = I2;
      wv[I2] = -1.f;
    }
    __syncthreads();
  }
  if (t < 64) {
    const int idx = sel[t];
    const float sv = allocp[(size_t)b * 1024 + idx];
    float ssum = sv;
#pragma unroll
    for (int off = 32; off; off >>= 1) ssum += __shfl_xor(ssum, off);
    outI[b * 64 + t] = (float)idx;
    outS[b * 64 + t] = sv / (ssum + 1e-12f);
  }
}

// ---------------------------------------------------------------------------
// Host launcher.  Workspace (floats), U = 16,777,216:
//   h [0,U) | obuf [U,2U) | carea [2U,3.5U)  -- peak 3.5U*4 B = 224 MiB.
// ---------------------------------------------------------------------------
extern "C" void kernel_launch(void* const* d_in, const int* in_sizes, int n_in,
                              void* d_out, int out_size, void* d_ws, size_t ws_size,
                              hipStream_t stream)
{
  (void)in_sizes; (void)n_in; (void)out_size; (void)ws_size;
  const float* x      = (const float*)d_in[0];
  const float* gumbel = (const float*)d_in[1];
  const float* emb_W  = (const float*)d_in[2];
  const float* emb_b  = (const float*)d_in[3];
  const float* Wq     = (const float*)d_in[4];
  const float* Wk     = (const float*)d_in[5];
  const float* Wv     = (const float*)d_in[6];
  const float* Wo     = (const float*)d_in[7];
  const float* ln1_g  = (const float*)d_in[8];
  const float* ln1_b  = (const float*)d_in[9];
  const float* ln2_g  = (const float*)d_in[10];
  const float* ln2_b  = (const float*)d_in[11];
  const float* ffn_W1 = (const float*)d_in[12];
  const float* ffn_b1 = (const float*)d_in[13];
  const float* ffn_W2 = (const float*)d_in[14];
  const float* ffn_b2 = (const float*)d_in[15];
  const float* sha_Wq = (const float*)d_in[16];
  const float* sha_Wk = (const float*)d_in[17];
  const float* aW1    = (const float*)d_in[18];
  const float* ab1    = (const float*)d_in[19];
  const float* aW2    = (const float*)d_in[20];
  const float* ab2    = (const float*)d_in[21];

  float* ws = (float*)d_ws;
  const size_t U = (size_t)BB * NN * DD;
  float* h     = ws;
  float* obuf  = ws + U;
  float* carea = ws + 2 * U;
  const size_t HC = U / 2;
  float* qc = carea;
  float* kc = carea + HC;
  float* vc = carea + 2 * HC;
  float* fbuf = carea;
  float* hmean  = carea;
  float* qvb    = carea + BB * DD;
  float* allocp = carea + 2 * BB * DD;
  float* wcopy  = allocp + (size_t)BB * NN;

  float* outW = (float*)d_out;
  float* outI = outW + (size_t)BB * NN;
  float* outS = outI + BB * KSEL;

  const dim3 blk(256);
  const int M = BB * NN;

  auto GEMM = [&](const float* A, int lda, const float* Bp, int ldb,
                  float* C, int ldc, const float* bias, const float* res,
                  int ldres, int Mm, int Nn, int Kk, int relu, int accum) {
    gemm128_kernel<<<dim3(Nn / 128, Mm / 128), blk, 0, stream>>>(
        A, lda, Bp, ldb, C, ldc, bias, res, ldres, Kk, relu, accum);
  };

  embed_kernel<<<dim3(M / 4), blk, 0, stream>>>(x, emb_W, emb_b, h);

  for (int i = 0; i < LL; ++i) {
    const float* wq  = Wq + (size_t)i * DD * DD;
    const float* wk  = Wk + (size_t)i * DD * DD;
    const float* wvp = Wv + (size_t)i * DD * DD;
    const float* wo  = Wo + (size_t)i * DD * DD;
    const float* w1  = ffn_W1 + (size_t)i * DD * DFF2;
    const float* b1  = ffn_b1 + (size_t)i * DFF2;
    const float* w2  = ffn_W2 + (size_t)i * DFF2 * DD;
    const float* b2  = ffn_b2 + (size_t)i * DD;

    for (int half = 0; half < 2; ++half) {
      const size_t roff = (size_t)half * (M / 2) * DD;
      const int Mc = M / 2;
      GEMM(h + roff, DD, wq,  DD, qc, DD, nullptr, nullptr, 0, Mc, DD, DD, 0, 0);
      GEMM(h + roff, DD, wk,  DD, kc, DD, nullptr, nullptr, 0, Mc, DD, DD, 0, 0);
      GEMM(h + roff, DD, wvp, DD, vc, DD, nullptr, nullptr, 0, Mc, DD, DD, 0, 0);
      attn_kernel<<<dim3(NN / 128, HH, BB / 2), blk, 0, stream>>>(qc, kc, vc, obuf + roff);
    }
    GEMM(obuf, DD, wo, DD, h, DD, nullptr, h, DD, M, DD, DD, 0, 0);
    ln_kernel<<<dim3(M / 4), blk, 0, stream>>>(h, h, ln1_g + i * DD, ln1_b + i * DD);

    for (int c = 0; c < 4; ++c) {
      GEMM(h, DD, w1 + c * 256, DFF2, obuf, 256, b1 + c * 256, nullptr, 0,
           M, 256, DD, 1, 0);
      GEMM(obuf, 256, w2 + (size_t)c * 256 * DD, DD, fbuf, DD,
           (c == 0) ? b2 : nullptr, (c == 0) ? h : nullptr, DD,
           M, DD, 256, 0, (c == 0) ? 0 : 1);
    }
    ln_kernel<<<dim3(M / 4), blk, 0, stream>>>(fbuf, h, ln2_g + i * DD, ln2_b + i * DD);
  }

  rowmean_kernel<<<dim3(BB), blk, 0, stream>>>(h, hmean);
  final_small_kernel<<<dim3(BB), blk, 0, stream>>>(hmean, sha_Wq, aW1, ab1, aW2, ab2, qvb, allocp);
  GEMM(h, DD, sha_Wk, DD, obuf, DD, nullptr, nullptr, 0, M, DD, DD, 0, 0);
  scores_kernel<<<dim3(BB), blk, 0, stream>>>(qvb, obuf, gumbel, outW, wcopy);
  topk_kernel<<<dim3(BB), blk, 0, stream>>>(wcopy, allocp, outI, outS);
}

// Round 6
// 12164.762 us; speedup vs baseline: 1.2400x; 1.2400x over previous
//
#include <hip/hip_runtime.h>
#include <math.h>

// Problem constants
#define BB   64
#define NN   1024
#define DIN  16
#define DD   256
#define HH   4
#define LL   3
#define DHH  64
#define DFF2 1024
#define KSEL 64

// ---------------------------------------------------------------------------
// Embedding: h[row, :] = x[row, :16] @ emb_W + emb_b.  4 rows per block.
// ---------------------------------------------------------------------------
__global__ __launch_bounds__(256) void embed_kernel(
    const float* __restrict__ x, const float* __restrict__ W,
    const float* __restrict__ bias, float* __restrict__ h)
{
  __shared__ float xs[4][DIN];
  const int t = threadIdx.x, w = t >> 6, lane = t & 63;
  const size_t row = (size_t)blockIdx.x * 4 + w;
  if (lane < DIN) xs[w][lane] = x[row * DIN + lane];
  __syncthreads();
#pragma unroll
  for (int j = 0; j < 4; ++j) {
    const int col = lane + j * 64;
    float acc = bias[col];
#pragma unroll
    for (int kk = 0; kk < DIN; ++kk) acc = fmaf(xs[w][kk], W[kk * DD + col], acc);
    h[row * DD + col] = acc;
  }
}

// ---------------------------------------------------------------------------
// fp32 GEMM: C[M,N] = A[M,K] @ B[K,N] (+bias)(+res)(relu)(accum)
// 128x128 tile, BK=8, single-buffer, 256 threads, 8x8 micro.
// A octets stored at stride-12 dwords (48 B, 16B-aligned): ty-octet reads
// land on distinct bank-quads (conflict-free) vs stride-8's 4-way.
// B loader (R3-proven geometry): brow = t>>5 (8 k-rows), bcq = t&31
// (32 col-quads), ONE float4/thread; rotate-interleave phys =
// (cq>>1)|((cq&1)<<4) so micro-tile reads at tx*4 / tx*4+64 are 2-way (free).
// ---------------------------------------------------------------------------
__global__ __launch_bounds__(256) void gemm128_kernel(
    const float* __restrict__ A, int lda,
    const float* __restrict__ Bm, int ldb,
    float* C, int ldc,
    const float* __restrict__ bias,
    const float* res, int ldres,
    int Kk, int relu, int accum)
{
  __shared__ __align__(16) float As[8][192];
  __shared__ __align__(16) float Bs[8][132];
  const int t = threadIdx.x;
  const int tx = t & 15, ty = t >> 4;
  const size_t row0 = (size_t)blockIdx.y * 128;
  const size_t col0 = (size_t)blockIdx.x * 128;
  // A loader: row = t>>1 (128 rows x 2 threads), k-quad = (t&1)*4
  const int arow = t >> 1, aq = (t & 1) * 4;
  const int acol = 12 * (arow >> 3) + (arow & 7);  // stride-12 octet layout
  // B loader: k-row = t>>5 (0..7), col-quad = t&31 (0..31)
  const int brow = t >> 5, bcq = t & 31;
  const int bp = ((bcq >> 1) | ((bcq & 1) << 4)) * 4;
  float acc[8][8] = {};
  const float* Aptr = A + (row0 + arow) * lda + aq;
  const float* Bptr = Bm + (size_t)brow * ldb + col0 + bcq * 4;
  for (int k0 = 0; k0 < Kk; k0 += 8) {
    const float4 av = *(const float4*)(Aptr + k0);
    const float4 bv = *(const float4*)(Bptr + (size_t)k0 * ldb);
    As[aq + 0][acol] = av.x; As[aq + 1][acol] = av.y;
    As[aq + 2][acol] = av.z; As[aq + 3][acol] = av.w;
    *(float4*)&Bs[brow][bp] = bv;
    __syncthreads();
#pragma unroll
    for (int kk = 0; kk < 8; ++kk) {
      const float4 x0 = *(const float4*)&As[kk][ty * 12];
      const float4 x1 = *(const float4*)&As[kk][ty * 12 + 4];
      const float4 y0 = *(const float4*)&Bs[kk][tx * 4];
      const float4 y1 = *(const float4*)&Bs[kk][tx * 4 + 64];
      const float aa[8] = {x0.x, x0.y, x0.z, x0.w, x1.x, x1.y, x1.z, x1.w};
      const float bb2[8] = {y0.x, y0.y, y0.z, y0.w, y1.x, y1.y, y1.z, y1.w};
#pragma unroll
      for (int i = 0; i < 8; ++i)
#pragma unroll
        for (int j = 0; j < 8; ++j)
          acc[i][j] = fmaf(aa[i], bb2[j], acc[i][j]);
    }
    __syncthreads();
  }
#pragma unroll
  for (int i = 0; i < 8; ++i) {
    const size_t r = row0 + ty * 8 + i;
    float* cp = C + r * (size_t)ldc + col0 + tx * 8;
    const float* rp = res ? res + r * (size_t)ldres + col0 + tx * 8 : nullptr;
#pragma unroll
    for (int j = 0; j < 8; ++j) {
      const size_t c = col0 + tx * 8 + j;
      float v = acc[i][j];
      if (bias) v += bias[c];
      if (rp)   v += rp[j];
      if (relu) v = fmaxf(v, 0.f);
      if (accum) v += cp[j];
      cp[j] = v;
    }
  }
}

// ---------------------------------------------------------------------------
// Flash attention v6, fp32.  ONE WAVE (64 threads) per (b, head, 64-q-rows).
// 8x8 micro-tiles -> F/R = 16 (VALU-bound, LDS below capacity at 3 waves/CU);
// softmax amortized over 8192 FMA/k-tile; single-wave barriers are cheap.
// Thread (A = t>>3, Bd = t&7):
//   QK phase: q-rows {A+8i} (interleaved), k-cols {Bd+8j}; row max/sum via
//             3-step shfl over the 8 Bd lanes.
//   PV phase: O rows {8A+i} (contiguous b128 Pt/V reads), cols {8Bd+j};
//             per-row alpha/l bounced through 64-float LDS arrays.
// LDS: Qn/KV/Pt [64][68] + alpha/l = 52736 B -> 3 single-wave blocks/CU.
// K/V register-prefetch under compute.
// ---------------------------------------------------------------------------
__global__ __launch_bounds__(64) void attn_kernel(
    const float* __restrict__ qb, const float* __restrict__ kb,
    const float* __restrict__ vb, float* __restrict__ ob)
{
  __shared__ __align__(16) float Qn[64 * 68];
  __shared__ __align__(16) float KV[64 * 68];
  __shared__ __align__(16) float Pt[64 * 68];
  __shared__ float alphaL[64];
  __shared__ float lrunL[64];
  const int t = threadIdx.x;
  const int A = t >> 3, Bd = t & 7;
  const int qt = blockIdx.x, hh = blockIdx.y, b = blockIdx.z;
  const size_t base = ((size_t)b * NN) * DD + (size_t)hh * DHH;
  const int srow = t >> 4, scq = t & 15;  // staging: rows srow+4u, quad scq

  // ---- stage Q + K0; prefetch V0 ----
  {
    const float* qp = qb + base + (size_t)(qt * 64) * DD + scq * 4;
    const float* kp = kb + base + scq * 4;
#pragma unroll
    for (int u = 0; u < 16; ++u) {
      const int r = srow + 4 * u;
      *(float4*)&Qn[r * 68 + scq * 4] = *(const float4*)(qp + (size_t)r * DD);
      *(float4*)&KV[r * 68 + scq * 4] = *(const float4*)(kp + (size_t)r * DD);
    }
  }
  lrunL[t] = 0.f;
  float4 vreg[16];
  {
    const float* vp = vb + base + scq * 4;
#pragma unroll
    for (int u = 0; u < 16; ++u)
      vreg[u] = *(const float4*)(vp + (size_t)(srow + 4 * u) * DD);
  }
  float mrun[8];
#pragma unroll
  for (int i = 0; i < 8; ++i) mrun[i] = -1e30f;
  float O[8][8] = {};
  __syncthreads();

  for (int kt = 0; kt < 16; ++kt) {
    // ---- S = Q K^T (rows A+8i, cols Bd+8j) ----
    float S[8][8];
#pragma unroll
    for (int i = 0; i < 8; ++i)
#pragma unroll
      for (int j = 0; j < 8; ++j) S[i][j] = 0.f;
#pragma unroll 2
    for (int dq = 0; dq < 16; ++dq) {
      float4 k4[8];
#pragma unroll
      for (int j = 0; j < 8; ++j)
        k4[j] = *(const float4*)&KV[(Bd + 8 * j) * 68 + dq * 4];
#pragma unroll
      for (int i = 0; i < 8; ++i) {
        const float4 q4 = *(const float4*)&Qn[(A + 8 * i) * 68 + dq * 4];
#pragma unroll
        for (int j = 0; j < 8; ++j)
          S[i][j] += q4.x * k4[j].x + q4.y * k4[j].y +
                     q4.z * k4[j].z + q4.w * k4[j].w;
      }
    }

    // ---- online softmax per q-row (8 local cols x 8 Bd lanes) ----
#pragma unroll
    for (int i = 0; i < 8; ++i) {
      float mt = -1e30f;
#pragma unroll
      for (int j = 0; j < 8; ++j) { S[i][j] *= 0.125f; mt = fmaxf(mt, S[i][j]); }
      mt = fmaxf(mt, __shfl_xor(mt, 1));
      mt = fmaxf(mt, __shfl_xor(mt, 2));
      mt = fmaxf(mt, __shfl_xor(mt, 4));
      const float mnew = fmaxf(mrun[i], mt);
      const float alpha = __expf(mrun[i] - mnew);
      mrun[i] = mnew;
      float rs = 0.f;
#pragma unroll
      for (int j = 0; j < 8; ++j) { S[i][j] = __expf(S[i][j] - mnew); rs += S[i][j]; }
      rs += __shfl_xor(rs, 1);
      rs += __shfl_xor(rs, 2);
      rs += __shfl_xor(rs, 4);
      if (Bd == 0) {
        alphaL[A + 8 * i] = alpha;
        lrunL[A + 8 * i] = lrunL[A + 8 * i] * alpha + rs;
      }
      // P^T scatter: Pt[c = Bd+8j][q = A+8i]
#pragma unroll
      for (int j = 0; j < 8; ++j)
        Pt[(Bd + 8 * j) * 68 + (A + 8 * i)] = S[i][j];
    }
    __syncthreads();  // bar A: K reads done; Pt/alpha visible

    // V regs -> KV
#pragma unroll
    for (int u = 0; u < 16; ++u)
      *(float4*)&KV[(srow + 4 * u) * 68 + scq * 4] = vreg[u];
    // prefetch K_{kt+1} (consumed after bar C)
    float4 kreg[16];
    {
      const float* kp = kb + base + (size_t)(((kt + 1) & 15) * 64) * DD + scq * 4;
#pragma unroll
      for (int u = 0; u < 16; ++u)
        kreg[u] = *(const float4*)(kp + (size_t)(srow + 4 * u) * DD);
    }
    __syncthreads();  // bar B: V visible

    // ---- O = O*alpha + P V (rows 8A+i, cols 8Bd+j) ----
#pragma unroll
    for (int i = 0; i < 8; ++i) {
      const float al = alphaL[8 * A + i];
#pragma unroll
      for (int j = 0; j < 8; ++j) O[i][j] *= al;
    }
#pragma unroll 4
    for (int c = 0; c < 64; ++c) {
      const float4 p0 = *(const float4*)&Pt[c * 68 + 8 * A];
      const float4 p1 = *(const float4*)&Pt[c * 68 + 8 * A + 4];
      const float4 v0 = *(const float4*)&KV[c * 68 + 8 * Bd];
      const float4 v1 = *(const float4*)&KV[c * 68 + 8 * Bd + 4];
      const float pp[8] = {p0.x, p0.y, p0.z, p0.w, p1.x, p1.y, p1.z, p1.w};
      const float vv[8] = {v0.x, v0.y, v0.z, v0.w, v1.x, v1.y, v1.z, v1.w};
#pragma unroll
      for (int i = 0; i < 8; ++i)
#pragma unroll
        for (int j = 0; j < 8; ++j)
          O[i][j] = fmaf(pp[i], vv[j], O[i][j]);
    }
    __syncthreads();  // bar C: V reads done

    // K regs -> KV; prefetch V_{kt+1} (consumed at next bar A)
#pragma unroll
    for (int u = 0; u < 16; ++u)
      *(float4*)&KV[(srow + 4 * u) * 68 + scq * 4] = kreg[u];
    {
      const float* vp = vb + base + (size_t)(((kt + 1) & 15) * 64) * DD + scq * 4;
#pragma unroll
      for (int u = 0; u < 16; ++u)
        vreg[u] = *(const float4*)(vp + (size_t)(srow + 4 * u) * DD);
    }
    __syncthreads();  // bar D: K visible
  }

  // ---- write O (rows 8A+i, d-cols 8Bd..8Bd+7) ----
#pragma unroll
  for (int i = 0; i < 8; ++i) {
    const int r = 8 * A + i;
    const float inv = 1.f / lrunL[r];
    const float4 o0 = {O[i][0] * inv, O[i][1] * inv, O[i][2] * inv, O[i][3] * inv};
    const float4 o1 = {O[i][4] * inv, O[i][5] * inv, O[i][6] * inv, O[i][7] * inv};
    float* op = ob + base + (size_t)(qt * 64 + r) * DD + 8 * Bd;
    *(float4*)op = o0;
    *(float4*)(op + 4) = o1;
  }
}

// ---------------------------------------------------------------------------
// LayerNorm over D=256, 4 rows/block (one wave per row, shfl reduce).
// ---------------------------------------------------------------------------
__global__ __launch_bounds__(256) void ln_kernel(
    const float* in, float* out,
    const float* __restrict__ g, const float* __restrict__ bb)
{
  const int t = threadIdx.x, w = t >> 6, lane = t & 63;
  const size_t row = (size_t)blockIdx.x * 4 + w;
  const float4 val = *(const float4*)(in + row * DD + lane * 4);
  float s = val.x + val.y + val.z + val.w;
#pragma unroll
  for (int off = 32; off; off >>= 1) s += __shfl_xor(s, off);
  const float mean = s * (1.f / 256.f);
  const float dx = val.x - mean, dy = val.y - mean, dz = val.z - mean, dw = val.w - mean;
  float ss = dx * dx + dy * dy + dz * dz + dw * dw;
#pragma unroll
  for (int off = 32; off; off >>= 1) ss += __shfl_xor(ss, off);
  const float inv = rsqrtf(ss * (1.f / 256.f) + 1e-5f);
  const float4 g4 = *(const float4*)(g + lane * 4);
  const float4 b4 = *(const float4*)(bb + lane * 4);
  float4 o4;
  o4.x = dx * inv * g4.x + b4.x;
  o4.y = dy * inv * g4.y + b4.y;
  o4.z = dz * inv * g4.z + b4.z;
  o4.w = dw * inv * g4.w + b4.w;
  *(float4*)(out + row * DD + lane * 4) = o4;
}

// ---------------------------------------------------------------------------
// h_mean[b, :] = mean over N of h[b, :, :]
// ---------------------------------------------------------------------------
__global__ __launch_bounds__(256) void rowmean_kernel(
    const float* __restrict__ h, float* __restrict__ hm)
{
  const int t = threadIdx.x, b = blockIdx.x;
  const float* p = h + (size_t)b * NN * DD + t;
  float acc = 0.f;
  for (int n = 0; n < NN; ++n) acc += p[(size_t)n * DD];
  hm[b * DD + t] = acc * (1.f / NN);
}

// ---------------------------------------------------------------------------
// Per-batch small heads: qv = h_mean@sha_Wq; alloc = softmax(relu(h_mean@W1+b1)@W2+b2)
// ---------------------------------------------------------------------------
__global__ __launch_bounds__(256) void final_small_kernel(
    const float* __restrict__ hm, const float* __restrict__ shaWq,
    const float* __restrict__ W1, const float* __restrict__ b1,
    const float* __restrict__ W2, const float* __restrict__ b2,
    float* __restrict__ qv, float* __restrict__ allocp)
{
  __shared__ float hs[256];
  __shared__ float mids[256];
  __shared__ float red[256];
  const int t = threadIdx.x, b = blockIdx.x;
  hs[t] = hm[b * 256 + t];
  __syncthreads();
  float a = 0.f, m2 = b1[t];
  for (int kk = 0; kk < 256; ++kk) {
    const float hv = hs[kk];
    a  = fmaf(hv, shaWq[kk * 256 + t], a);
    m2 = fmaf(hv, W1[kk * 256 + t], m2);
  }
  qv[b * 256 + t] = a;
  mids[t] = fmaxf(m2, 0.f);
  __syncthreads();
  float lg[4];
#pragma unroll
  for (int j = 0; j < 4; ++j) {
    const int n = t + j * 256;
    float acc2 = b2[n];
    for (int kk = 0; kk < 256; ++kk) acc2 = fmaf(mids[kk], W2[kk * 1024 + n], acc2);
    lg[j] = acc2;
  }
  float m = fmaxf(fmaxf(lg[0], lg[1]), fmaxf(lg[2], lg[3]));
  red[t] = m; __syncthreads();
  for (int s2 = 128; s2; s2 >>= 1) { if (t < s2) red[t] = fmaxf(red[t], red[t + s2]); __syncthreads(); }
  m = red[0]; __syncthreads();
  float e[4]; float ls = 0.f;
#pragma unroll
  for (int j = 0; j < 4; ++j) { e[j] = expf(lg[j] - m); ls += e[j]; }
  red[t] = ls; __syncthreads();
  for (int s2 = 128; s2; s2 >>= 1) { if (t < s2) red[t] += red[t + s2]; __syncthreads(); }
  const float invs = 1.f / red[0];
#pragma unroll
  for (int j = 0; j < 4; ++j) allocp[(size_t)b * 1024 + t + j * 256] = e[j] * invs;
}

// ---------------------------------------------------------------------------
// scores[b,n] = dot(qv[b], kv[b,n])/16; weights = softmax((scores+g)/0.5)
// ---------------------------------------------------------------------------
__global__ __launch_bounds__(256) void scores_kernel(
    const float* __restrict__ qv, const float* __restrict__ kv,
    const float* __restrict__ gum, float* __restrict__ outW,
    float* __restrict__ wcopy)
{
  __shared__ __align__(16) float qs[256];
  __shared__ float sc[1024];
  __shared__ float red[256];
  const int t = threadIdx.x, b = blockIdx.x;
  const int w = t >> 6, lane = t & 63;
  qs[t] = qv[b * 256 + t];
  __syncthreads();
  const float4 myq = *(const float4*)&qs[lane * 4];
  for (int n = w; n < 1024; n += 4) {
    const float4 k4 = *(const float4*)(kv + ((size_t)b * 1024 + n) * 256 + lane * 4);
    float d = myq.x * k4.x + myq.y * k4.y + myq.z * k4.z + myq.w * k4.w;
#pragma unroll
    for (int off = 32; off; off >>= 1) d += __shfl_xor(d, off);
    if (lane == 0) sc[n] = d * (1.f / 16.f);
  }
  __syncthreads();
  float z[4];
#pragma unroll
  for (int j = 0; j < 4; ++j) {
    const int n = t + j * 256;
    z[j] = (sc[n] + gum[(size_t)b * 1024 + n]) * 2.0f;  // /TAU, TAU=0.5
  }
  float m = fmaxf(fmaxf(z[0], z[1]), fmaxf(z[2], z[3]));
  red[t] = m; __syncthreads();
  for (int s2 = 128; s2; s2 >>= 1) { if (t < s2) red[t] = fmaxf(red[t], red[t + s2]); __syncthreads(); }
  m = red[0]; __syncthreads();
  float e[4]; float ls = 0.f;
#pragma unroll
  for (int j = 0; j < 4; ++j) { e[j] = expf(z[j] - m); ls += e[j]; }
  red[t] = ls; __syncthreads();
  for (int s2 = 128; s2; s2 >>= 1) { if (t < s2) red[t] += red[t + s2]; __syncthreads(); }
  const float invs = 1.f / red[0];
#pragma unroll
  for (int j = 0; j < 4; ++j) {
    const int n = t + j * 256;
    const float wv = e[j] * invs;
    outW[(size_t)b * 1024 + n] = wv;
    wcopy[(size_t)b * 1024 + n] = wv;
  }
}

// ---------------------------------------------------------------------------
// Top-64 (descending, ties -> lower index, matching jax.lax.top_k) + sel gather.
// ---------------------------------------------------------------------------
__global__ __launch_bounds__(256) void topk_kernel(
    const float* __restrict__ wcopy, const float* __restrict__ allocp,
    float* __restrict__ outI, float* __restrict__ outS)
{
  __shared__ float wv[1024];
  __shared__ float rv[4];
  __shared__ int   ri[4];
  __shared__ int   sel[64];
  const int t = threadIdx.x, b = blockIdx.x;
  const int w = t >> 6, lane = t & 63;
#pragma unroll
  for (int j = 0; j < 4; ++j) wv[t * 4 + j] = wcopy[(size_t)b * 1024 + t * 4 + j];
  __syncthreads();
  for (int it = 0; it < 64; ++it) {
    float bv = -1.f; int bi = 1 << 20;
#pragma unroll
    for (int j = 0; j < 4; ++j) {
      const int n = t * 4 + j;
      const float v2 = wv[n];
      if (v2 > bv || (v2 == bv && n < bi)) { bv = v2; bi = n; }
    }
#pragma unroll
    for (int off = 32; off; off >>= 1) {
      const float ov = __shfl_xor(bv, off);
      const int   oi = __shfl_xor(bi, off);
      if (ov > bv || (ov == bv && oi < bi)) { bv = ov; bi = oi; }
    }
    if (lane == 0) { rv[w] = bv; ri[w] = bi; }
    __syncthreads();
    if (t == 0) {
      float B2 = rv[0]; int I2 = ri[0];
      for (int u = 1; u < 4; ++u)
        if (rv[u] > B2 || (rv[u] == B2 && ri[u] < I2)) { B2 = rv[u]; I2 = ri[u]; }
      sel[it] = I2;
      wv[I2] = -1.f;
    }
    __syncthreads();
  }
  if (t < 64) {
    const int idx = sel[t];
    const float sv = allocp[(size_t)b * 1024 + idx];
    float ssum = sv;
#pragma unroll
    for (int off = 32; off; off >>= 1) ssum += __shfl_xor(ssum, off);
    outI[b * 64 + t] = (float)idx;
    outS[b * 64 + t] = sv / (ssum + 1e-12f);
  }
}

// ---------------------------------------------------------------------------
// Host launcher.  Workspace (floats), U = 16,777,216:
//   h [0,U) | obuf [U,2U) | carea [2U,3.5U)  -- peak 3.5U*4 B = 224 MiB.
// ---------------------------------------------------------------------------
extern "C" void kernel_launch(void* const* d_in, const int* in_sizes, int n_in,
                              void* d_out, int out_size, void* d_ws, size_t ws_size,
                              hipStream_t stream)
{
  (void)in_sizes; (void)n_in; (void)out_size; (void)ws_size;
  const float* x      = (const float*)d_in[0];
  const float* gumbel = (const float*)d_in[1];
  const float* emb_W  = (const float*)d_in[2];
  const float* emb_b  = (const float*)d_in[3];
  const float* Wq     = (const float*)d_in[4];
  const float* Wk     = (const float*)d_in[5];
  const float* Wv     = (const float*)d_in[6];
  const float* Wo     = (const float*)d_in[7];
  const float* ln1_g  = (const float*)d_in[8];
  const float* ln1_b  = (const float*)d_in[9];
  const float* ln2_g  = (const float*)d_in[10];
  const float* ln2_b  = (const float*)d_in[11];
  const float* ffn_W1 = (const float*)d_in[12];
  const float* ffn_b1 = (const float*)d_in[13];
  const float* ffn_W2 = (const float*)d_in[14];
  const float* ffn_b2 = (const float*)d_in[15];
  const float* sha_Wq = (const float*)d_in[16];
  const float* sha_Wk = (const float*)d_in[17];
  const float* aW1    = (const float*)d_in[18];
  const float* ab1    = (const float*)d_in[19];
  const float* aW2    = (const float*)d_in[20];
  const float* ab2    = (const float*)d_in[21];

  float* ws = (float*)d_ws;
  const size_t U = (size_t)BB * NN * DD;
  float* h     = ws;
  float* obuf  = ws + U;
  float* carea = ws + 2 * U;
  const size_t HC = U / 2;
  float* qc = carea;
  float* kc = carea + HC;
  float* vc = carea + 2 * HC;
  float* fbuf = carea;
  float* hmean  = carea;
  float* qvb    = carea + BB * DD;
  float* allocp = carea + 2 * BB * DD;
  float* wcopy  = allocp + (size_t)BB * NN;

  float* outW = (float*)d_out;
  float* outI = outW + (size_t)BB * NN;
  float* outS = outI + BB * KSEL;

  const dim3 blk(256);
  const int M = BB * NN;

  auto GEMM = [&](const float* A, int lda, const float* Bp, int ldb,
                  float* C, int ldc, const float* bias, const float* res,
                  int ldres, int Mm, int Nn, int Kk, int relu, int accum) {
    gemm128_kernel<<<dim3(Nn / 128, Mm / 128), blk, 0, stream>>>(
        A, lda, Bp, ldb, C, ldc, bias, res, ldres, Kk, relu, accum);
  };

  embed_kernel<<<dim3(M / 4), blk, 0, stream>>>(x, emb_W, emb_b, h);

  for (int i = 0; i < LL; ++i) {
    const float* wq  = Wq + (size_t)i * DD * DD;
    const float* wk  = Wk + (size_t)i * DD * DD;
    const float* wvp = Wv + (size_t)i * DD * DD;
    const float* wo  = Wo + (size_t)i * DD * DD;
    const float* w1  = ffn_W1 + (size_t)i * DD * DFF2;
    const float* b1  = ffn_b1 + (size_t)i * DFF2;
    const float* w2  = ffn_W2 + (size_t)i * DFF2 * DD;
    const float* b2  = ffn_b2 + (size_t)i * DD;

    for (int half = 0; half < 2; ++half) {
      const size_t roff = (size_t)half * (M / 2) * DD;
      const int Mc = M / 2;
      GEMM(h + roff, DD, wq,  DD, qc, DD, nullptr, nullptr, 0, Mc, DD, DD, 0, 0);
      GEMM(h + roff, DD, wk,  DD, kc, DD, nullptr, nullptr, 0, Mc, DD, DD, 0, 0);
      GEMM(h + roff, DD, wvp, DD, vc, DD, nullptr, nullptr, 0, Mc, DD, DD, 0, 0);
      attn_kernel<<<dim3(NN / 64, HH, BB / 2), dim3(64), 0, stream>>>(qc, kc, vc, obuf + roff);
    }
    GEMM(obuf, DD, wo, DD, h, DD, nullptr, h, DD, M, DD, DD, 0, 0);
    ln_kernel<<<dim3(M / 4), blk, 0, stream>>>(h, h, ln1_g + i * DD, ln1_b + i * DD);

    for (int c = 0; c < 4; ++c) {
      GEMM(h, DD, w1 + c * 256, DFF2, obuf, 256, b1 + c * 256, nullptr, 0,
           M, 256, DD, 1, 0);
      GEMM(obuf, 256, w2 + (size_t)c * 256 * DD, DD, fbuf, DD,
           (c == 0) ? b2 : nullptr, (c == 0) ? h : nullptr, DD,
           M, DD, 256, 0, (c == 0) ? 0 : 1);
    }
    ln_kernel<<<dim3(M / 4), blk, 0, stream>>>(fbuf, h, ln2_g + i * DD, ln2_b + i * DD);
  }

  rowmean_kernel<<<dim3(BB), blk, 0, stream>>>(h, hmean);
  final_small_kernel<<<dim3(BB), blk, 0, stream>>>(hmean, sha_Wq, aW1, ab1, aW2, ab2, qvb, allocp);
  GEMM(h, DD, sha_Wk, DD, obuf, DD, nullptr, nullptr, 0, M, DD, DD, 0, 0);
  scores_kernel<<<dim3(BB), blk, 0, stream>>>(qvb, obuf, gumbel, outW, wcopy);
  topk_kernel<<<dim3(BB), blk, 0, stream>>>(wcopy, allocp, outI, outS);
}

// Round 7
// 12069.137 us; speedup vs baseline: 1.2499x; 1.0079x over previous
//
#include <hip/hip_runtime.h>
#include <math.h>

// Problem constants
#define BB   64
#define NN   1024
#define DIN  16
#define DD   256
#define HH   4
#define LL   3
#define DHH  64
#define DFF2 1024
#define KSEL 64

// ---------------------------------------------------------------------------
// Embedding: h[row, :] = x[row, :16] @ emb_W + emb_b.  4 rows per block.
// ---------------------------------------------------------------------------
__global__ __launch_bounds__(256) void embed_kernel(
    const float* __restrict__ x, const float* __restrict__ W,
    const float* __restrict__ bias, float* __restrict__ h)
{
  __shared__ float xs[4][DIN];
  const int t = threadIdx.x, w = t >> 6, lane = t & 63;
  const size_t row = (size_t)blockIdx.x * 4 + w;
  if (lane < DIN) xs[w][lane] = x[row * DIN + lane];
  __syncthreads();
#pragma unroll
  for (int j = 0; j < 4; ++j) {
    const int col = lane + j * 64;
    float acc = bias[col];
#pragma unroll
    for (int kk = 0; kk < DIN; ++kk) acc = fmaf(xs[w][kk], W[kk * DD + col], acc);
    h[row * DD + col] = acc;
  }
}

// ---------------------------------------------------------------------------
// fp32 GEMM: C[M,N] = A[M,K] @ B[K,N] (+bias)(+res)(relu)(accum)
// 128x128 tile, BK=8, single-buffer, 256 threads, 8x8 micro.
// A octets at stride-12 dwords (conflict-free ty-octet reads);
// B rotate-interleaved col-quads (2-way reads).  Proven in R6.
// ---------------------------------------------------------------------------
__global__ __launch_bounds__(256) void gemm128_kernel(
    const float* __restrict__ A, int lda,
    const float* __restrict__ Bm, int ldb,
    float* C, int ldc,
    const float* __restrict__ bias,
    const float* res, int ldres,
    int Kk, int relu, int accum)
{
  __shared__ __align__(16) float As[8][192];
  __shared__ __align__(16) float Bs[8][132];
  const int t = threadIdx.x;
  const int tx = t & 15, ty = t >> 4;
  const size_t row0 = (size_t)blockIdx.y * 128;
  const size_t col0 = (size_t)blockIdx.x * 128;
  const int arow = t >> 1, aq = (t & 1) * 4;
  const int acol = 12 * (arow >> 3) + (arow & 7);  // stride-12 octet layout
  const int brow = t >> 5, bcq = t & 31;
  const int bp = ((bcq >> 1) | ((bcq & 1) << 4)) * 4;
  float acc[8][8] = {};
  const float* Aptr = A + (row0 + arow) * lda + aq;
  const float* Bptr = Bm + (size_t)brow * ldb + col0 + bcq * 4;
  for (int k0 = 0; k0 < Kk; k0 += 8) {
    const float4 av = *(const float4*)(Aptr + k0);
    const float4 bv = *(const float4*)(Bptr + (size_t)k0 * ldb);
    As[aq + 0][acol] = av.x; As[aq + 1][acol] = av.y;
    As[aq + 2][acol] = av.z; As[aq + 3][acol] = av.w;
    *(float4*)&Bs[brow][bp] = bv;
    __syncthreads();
#pragma unroll
    for (int kk = 0; kk < 8; ++kk) {
      const float4 x0 = *(const float4*)&As[kk][ty * 12];
      const float4 x1 = *(const float4*)&As[kk][ty * 12 + 4];
      const float4 y0 = *(const float4*)&Bs[kk][tx * 4];
      const float4 y1 = *(const float4*)&Bs[kk][tx * 4 + 64];
      const float aa[8] = {x0.x, x0.y, x0.z, x0.w, x1.x, x1.y, x1.z, x1.w};
      const float bb2[8] = {y0.x, y0.y, y0.z, y0.w, y1.x, y1.y, y1.z, y1.w};
#pragma unroll
      for (int i = 0; i < 8; ++i)
#pragma unroll
        for (int j = 0; j < 8; ++j)
          acc[i][j] = fmaf(aa[i], bb2[j], acc[i][j]);
    }
    __syncthreads();
  }
#pragma unroll
  for (int i = 0; i < 8; ++i) {
    const size_t r = row0 + ty * 8 + i;
    float* cp = C + r * (size_t)ldc + col0 + tx * 8;
    const float* rp = res ? res + r * (size_t)ldres + col0 + tx * 8 : nullptr;
#pragma unroll
    for (int j = 0; j < 8; ++j) {
      const size_t c = col0 + tx * 8 + j;
      float v = acc[i][j];
      if (bias) v += bias[c];
      if (rp)   v += rp[j];
      if (relu) v = fmaxf(v, 0.f);
      if (accum) v += cp[j];
      cp[j] = v;
    }
  }
}

// ---------------------------------------------------------------------------
// Flash attention v7 = R6's v6 structure + two fixes:
//  (a) __launch_bounds__(64, 1): 512-VGPR budget -> kreg/vreg/S/O (~280 regs)
//      fit with ZERO scratch spill (R6: VGPR capped at 132, 1.08 GB spill
//      traffic per dispatch, VALUBusy 31%).
//  (b) XCD-aware flat-grid decode: all 64 blocks of a batch satisfy
//      f mod 8 == b mod 8 -> one XCD owns each batch's K/V stream
//      (R6 FETCH was 8x ideal from cross-XCD re-fetch).
// Structure: ONE WAVE per (b, head, 64 q-rows); 8x8 micro (F/R=16);
// K/V time-share one LDS buffer with register prefetch under compute;
// P^T through LDS (b128-amortized); all hot reads 8-distinct-address
// (LDS broadcast-cheap).  LDS 52736 B -> 3 single-wave blocks/CU.
// ---------------------------------------------------------------------------
__global__ __launch_bounds__(64, 1) void attn_kernel(
    const float* __restrict__ qb, const float* __restrict__ kb,
    const float* __restrict__ vb, float* __restrict__ ob)
{
  __shared__ __align__(16) float Qn[64 * 68];
  __shared__ __align__(16) float KV[64 * 68];
  __shared__ __align__(16) float Pt[64 * 68];
  __shared__ float alphaL[64];
  __shared__ float lrunL[64];
  const int t = threadIdx.x;
  const int A = t >> 3, Bd = t & 7;
  // XCD-aware decode: f mod 32 == batch  ->  f mod 8 == b mod 8 (fixed XCD)
  const int f = blockIdx.x;
  const int b = f & 31;          // 0..31 (batch within this half-dispatch)
  const int rest = f >> 5;       // 0..63
  const int qt = rest & 15, hh = rest >> 4;
  const size_t base = ((size_t)b * NN) * DD + (size_t)hh * DHH;
  const int srow = t >> 4, scq = t & 15;  // staging: rows srow+4u, quad scq

  // ---- stage Q + K0; prefetch V0 ----
  {
    const float* qp = qb + base + (size_t)(qt * 64) * DD + scq * 4;
    const float* kp = kb + base + scq * 4;
#pragma unroll
    for (int u = 0; u < 16; ++u) {
      const int r = srow + 4 * u;
      *(float4*)&Qn[r * 68 + scq * 4] = *(const float4*)(qp + (size_t)r * DD);
      *(float4*)&KV[r * 68 + scq * 4] = *(const float4*)(kp + (size_t)r * DD);
    }
  }
  lrunL[t] = 0.f;
  float4 vreg[16];
  {
    const float* vp = vb + base + scq * 4;
#pragma unroll
    for (int u = 0; u < 16; ++u)
      vreg[u] = *(const float4*)(vp + (size_t)(srow + 4 * u) * DD);
  }
  float mrun[8];
#pragma unroll
  for (int i = 0; i < 8; ++i) mrun[i] = -1e30f;
  float O[8][8] = {};
  __syncthreads();

  for (int kt = 0; kt < 16; ++kt) {
    // ---- S = Q K^T (rows A+8i, cols Bd+8j) ----
    float S[8][8];
#pragma unroll
    for (int i = 0; i < 8; ++i)
#pragma unroll
      for (int j = 0; j < 8; ++j) S[i][j] = 0.f;
#pragma unroll 2
    for (int dq = 0; dq < 16; ++dq) {
      float4 k4[8];
#pragma unroll
      for (int j = 0; j < 8; ++j)
        k4[j] = *(const float4*)&KV[(Bd + 8 * j) * 68 + dq * 4];
#pragma unroll
      for (int i = 0; i < 8; ++i) {
        const float4 q4 = *(const float4*)&Qn[(A + 8 * i) * 68 + dq * 4];
#pragma unroll
        for (int j = 0; j < 8; ++j)
          S[i][j] += q4.x * k4[j].x + q4.y * k4[j].y +
                     q4.z * k4[j].z + q4.w * k4[j].w;
      }
    }

    // ---- online softmax per q-row (8 local cols x 8 Bd lanes) ----
#pragma unroll
    for (int i = 0; i < 8; ++i) {
      float mt = -1e30f;
#pragma unroll
      for (int j = 0; j < 8; ++j) { S[i][j] *= 0.125f; mt = fmaxf(mt, S[i][j]); }
      mt = fmaxf(mt, __shfl_xor(mt, 1));
      mt = fmaxf(mt, __shfl_xor(mt, 2));
      mt = fmaxf(mt, __shfl_xor(mt, 4));
      const float mnew = fmaxf(mrun[i], mt);
      const float alpha = __expf(mrun[i] - mnew);
      mrun[i] = mnew;
      float rs = 0.f;
#pragma unroll
      for (int j = 0; j < 8; ++j) { S[i][j] = __expf(S[i][j] - mnew); rs += S[i][j]; }
      rs += __shfl_xor(rs, 1);
      rs += __shfl_xor(rs, 2);
      rs += __shfl_xor(rs, 4);
      if (Bd == 0) {
        alphaL[A + 8 * i] = alpha;
        lrunL[A + 8 * i] = lrunL[A + 8 * i] * alpha + rs;
      }
      // P^T scatter: Pt[c = Bd+8j][q = A+8i]
#pragma unroll
      for (int j = 0; j < 8; ++j)
        Pt[(Bd + 8 * j) * 68 + (A + 8 * i)] = S[i][j];
    }
    __syncthreads();  // bar A: K reads done; Pt/alpha visible

    // V regs -> KV
#pragma unroll
    for (int u = 0; u < 16; ++u)
      *(float4*)&KV[(srow + 4 * u) * 68 + scq * 4] = vreg[u];
    // prefetch K_{kt+1} (consumed after bar C)
    float4 kreg[16];
    {
      const float* kp = kb + base + (size_t)(((kt + 1) & 15) * 64) * DD + scq * 4;
#pragma unroll
      for (int u = 0; u < 16; ++u)
        kreg[u] = *(const float4*)(kp + (size_t)(srow + 4 * u) * DD);
    }
    __syncthreads();  // bar B: V visible

    // ---- O = O*alpha + P V (rows 8A+i, cols 8Bd+j) ----
#pragma unroll
    for (int i = 0; i < 8; ++i) {
      const float al = alphaL[8 * A + i];
#pragma unroll
      for (int j = 0; j < 8; ++j) O[i][j] *= al;
    }
#pragma unroll 4
    for (int c = 0; c < 64; ++c) {
      const float4 p0 = *(const float4*)&Pt[c * 68 + 8 * A];
      const float4 p1 = *(const float4*)&Pt[c * 68 + 8 * A + 4];
      const float4 v0 = *(const float4*)&KV[c * 68 + 8 * Bd];
      const float4 v1 = *(const float4*)&KV[c * 68 + 8 * Bd + 4];
      const float pp[8] = {p0.x, p0.y, p0.z, p0.w, p1.x, p1.y, p1.z, p1.w};
      const float vv[8] = {v0.x, v0.y, v0.z, v0.w, v1.x, v1.y, v1.z, v1.w};
#pragma unroll
      for (int i = 0; i < 8; ++i)
#pragma unroll
        for (int j = 0; j < 8; ++j)
          O[i][j] = fmaf(pp[i], vv[j], O[i][j]);
    }
    __syncthreads();  // bar C: V reads done

    // K regs -> KV; prefetch V_{kt+1} (consumed at next bar A)
#pragma unroll
    for (int u = 0; u < 16; ++u)
      *(float4*)&KV[(srow + 4 * u) * 68 + scq * 4] = kreg[u];
    {
      const float* vp = vb + base + (size_t)(((kt + 1) & 15) * 64) * DD + scq * 4;
#pragma unroll
      for (int u = 0; u < 16; ++u)
        vreg[u] = *(const float4*)(vp + (size_t)(srow + 4 * u) * DD);
    }
    __syncthreads();  // bar D: K visible
  }

  // ---- write O (rows 8A+i, d-cols 8Bd..8Bd+7) ----
#pragma unroll
  for (int i = 0; i < 8; ++i) {
    const int r = 8 * A + i;
    const float inv = 1.f / lrunL[r];
    const float4 o0 = {O[i][0] * inv, O[i][1] * inv, O[i][2] * inv, O[i][3] * inv};
    const float4 o1 = {O[i][4] * inv, O[i][5] * inv, O[i][6] * inv, O[i][7] * inv};
    float* op = ob + base + (size_t)(qt * 64 + r) * DD + 8 * Bd;
    *(float4*)op = o0;
    *(float4*)(op + 4) = o1;
  }
}

// ---------------------------------------------------------------------------
// LayerNorm over D=256, 4 rows/block (one wave per row, shfl reduce).
// ---------------------------------------------------------------------------
__global__ __launch_bounds__(256) void ln_kernel(
    const float* in, float* out,
    const float* __restrict__ g, const float* __restrict__ bb)
{
  const int t = threadIdx.x, w = t >> 6, lane = t & 63;
  const size_t row = (size_t)blockIdx.x * 4 + w;
  const float4 val = *(const float4*)(in + row * DD + lane * 4);
  float s = val.x + val.y + val.z + val.w;
#pragma unroll
  for (int off = 32; off; off >>= 1) s += __shfl_xor(s, off);
  const float mean = s * (1.f / 256.f);
  const float dx = val.x - mean, dy = val.y - mean, dz = val.z - mean, dw = val.w - mean;
  float ss = dx * dx + dy * dy + dz * dz + dw * dw;
#pragma unroll
  for (int off = 32; off; off >>= 1) ss += __shfl_xor(ss, off);
  const float inv = rsqrtf(ss * (1.f / 256.f) + 1e-5f);
  const float4 g4 = *(const float4*)(g + lane * 4);
  const float4 b4 = *(const float4*)(bb + lane * 4);
  float4 o4;
  o4.x = dx * inv * g4.x + b4.x;
  o4.y = dy * inv * g4.y + b4.y;
  o4.z = dz * inv * g4.z + b4.z;
  o4.w = dw * inv * g4.w + b4.w;
  *(float4*)(out + row * DD + lane * 4) = o4;
}

// ---------------------------------------------------------------------------
// h_mean[b, :] = mean over N of h[b, :, :]
// ---------------------------------------------------------------------------
__global__ __launch_bounds__(256) void rowmean_kernel(
    const float* __restrict__ h, float* __restrict__ hm)
{
  const int t = threadIdx.x, b = blockIdx.x;
  const float* p = h + (size_t)b * NN * DD + t;
  float acc = 0.f;
  for (int n = 0; n < NN; ++n) acc += p[(size_t)n * DD];
  hm[b * DD + t] = acc * (1.f / NN);
}

// ---------------------------------------------------------------------------
// Per-batch small heads: qv = h_mean@sha_Wq; alloc = softmax(relu(h_mean@W1+b1)@W2+b2)
// ---------------------------------------------------------------------------
__global__ __launch_bounds__(256) void final_small_kernel(
    const float* __restrict__ hm, const float* __restrict__ shaWq,
    const float* __restrict__ W1, const float* __restrict__ b1,
    const float* __restrict__ W2, const float* __restrict__ b2,
    float* __restrict__ qv, float* __restrict__ allocp)
{
  __shared__ float hs[256];
  __shared__ float mids[256];
  __shared__ float red[256];
  const int t = threadIdx.x, b = blockIdx.x;
  hs[t] = hm[b * 256 + t];
  __syncthreads();
  float a = 0.f, m2 = b1[t];
  for (int kk = 0; kk < 256; ++kk) {
    const float hv = hs[kk];
    a  = fmaf(hv, shaWq[kk * 256 + t], a);
    m2 = fmaf(hv, W1[kk * 256 + t], m2);
  }
  qv[b * 256 + t] = a;
  mids[t] = fmaxf(m2, 0.f);
  __syncthreads();
  float lg[4];
#pragma unroll
  for (int j = 0; j < 4; ++j) {
    const int n = t + j * 256;
    float acc2 = b2[n];
    for (int kk = 0; kk < 256; ++kk) acc2 = fmaf(mids[kk], W2[kk * 1024 + n], acc2);
    lg[j] = acc2;
  }
  float m = fmaxf(fmaxf(lg[0], lg[1]), fmaxf(lg[2], lg[3]));
  red[t] = m; __syncthreads();
  for (int s2 = 128; s2; s2 >>= 1) { if (t < s2) red[t] = fmaxf(red[t], red[t + s2]); __syncthreads(); }
  m = red[0]; __syncthreads();
  float e[4]; float ls = 0.f;
#pragma unroll
  for (int j = 0; j < 4; ++j) { e[j] = expf(lg[j] - m); ls += e[j]; }
  red[t] = ls; __syncthreads();
  for (int s2 = 128; s2; s2 >>= 1) { if (t < s2) red[t] += red[t + s2]; __syncthreads(); }
  const float invs = 1.f / red[0];
#pragma unroll
  for (int j = 0; j < 4; ++j) allocp[(size_t)b * 1024 + t + j * 256] = e[j] * invs;
}

// ---------------------------------------------------------------------------
// scores[b,n] = dot(qv[b], kv[b,n])/16; weights = softmax((scores+g)/0.5)
// ---------------------------------------------------------------------------
__global__ __launch_bounds__(256) void scores_kernel(
    const float* __restrict__ qv, const float* __restrict__ kv,
    const float* __restrict__ gum, float* __restrict__ outW,
    float* __restrict__ wcopy)
{
  __shared__ __align__(16) float qs[256];
  __shared__ float sc[1024];
  __shared__ float red[256];
  const int t = threadIdx.x, b = blockIdx.x;
  const int w = t >> 6, lane = t & 63;
  qs[t] = qv[b * 256 + t];
  __syncthreads();
  const float4 myq = *(const float4*)&qs[lane * 4];
  for (int n = w; n < 1024; n += 4) {
    const float4 k4 = *(const float4*)(kv + ((size_t)b * 1024 + n) * 256 + lane * 4);
    float d = myq.x * k4.x + myq.y * k4.y + myq.z * k4.z + myq.w * k4.w;
#pragma unroll
    for (int off = 32; off; off >>= 1) d += __shfl_xor(d, off);
    if (lane == 0) sc[n] = d * (1.f / 16.f);
  }
  __syncthreads();
  float z[4];
#pragma unroll
  for (int j = 0; j < 4; ++j) {
    const int n = t + j * 256;
    z[j] = (sc[n] + gum[(size_t)b * 1024 + n]) * 2.0f;  // /TAU, TAU=0.5
  }
  float m = fmaxf(fmaxf(z[0], z[1]), fmaxf(z[2], z[3]));
  red[t] = m; __syncthreads();
  for (int s2 = 128; s2; s2 >>= 1) { if (t < s2) red[t] = fmaxf(red[t], red[t + s2]); __syncthreads(); }
  m = red[0]; __syncthreads();
  float e[4]; float ls = 0.f;
#pragma unroll
  for (int j = 0; j < 4; ++j) { e[j] = expf(z[j] - m); ls += e[j]; }
  red[t] = ls; __syncthreads();
  for (int s2 = 128; s2; s2 >>= 1) { if (t < s2) red[t] += red[t + s2]; __syncthreads(); }
  const float invs = 1.f / red[0];
#pragma unroll
  for (int j = 0; j < 4; ++j) {
    const int n = t + j * 256;
    const float wv = e[j] * invs;
    outW[(size_t)b * 1024 + n] = wv;
    wcopy[(size_t)b * 1024 + n] = wv;
  }
}

// ---------------------------------------------------------------------------
// Top-64 (descending, ties -> lower index, matching jax.lax.top_k) + sel gather.
// ---------------------------------------------------------------------------
__global__ __launch_bounds__(256) void topk_kernel(
    const float* __restrict__ wcopy, const float* __restrict__ allocp,
    float* __restrict__ outI, float* __restrict__ outS)
{
  __shared__ float wv[1024];
  __shared__ float rv[4];
  __shared__ int   ri[4];
  __shared__ int   sel[64];
  const int t = threadIdx.x, b = blockIdx.x;
  const int w = t >> 6, lane = t & 63;
#pragma unroll
  for (int j = 0; j < 4; ++j) wv[t * 4 + j] = wcopy[(size_t)b * 1024 + t * 4 + j];
  __syncthreads();
  for (int it = 0; it < 64; ++it) {
    float bv = -1.f; int bi = 1 << 20;
#pragma unroll
    for (int j = 0; j < 4; ++j) {
      const int n = t * 4 + j;
      const float v2 = wv[n];
      if (v2 > bv || (v2 == bv && n < bi)) { bv = v2; bi = n; }
    }
#pragma unroll
    for (int off = 32; off; off >>= 1) {
      const float ov = __shfl_xor(bv, off);
      const int   oi = __shfl_xor(bi, off);
      if (ov > bv || (ov == bv && oi < bi)) { bv = ov; bi = oi; }
    }
    if (lane == 0) { rv[w] = bv; ri[w] = bi; }
    __syncthreads();
    if (t == 0) {
      float B2 = rv[0]; int I2 = ri[0];
      for (int u = 1; u < 4; ++u)
        if (rv[u] > B2 || (rv[u] == B2 && ri[u] < I2)) { B2 = rv[u]; I2 = ri[u]; }
      sel[it] = I2;
      wv[I2] = -1.f;
    }
    __syncthreads();
  }
  if (t < 64) {
    const int idx = sel[t];
    const float sv = allocp[(size_t)b * 1024 + idx];
    float ssum = sv;
#pragma unroll
    for (int off = 32; off; off >>= 1) ssum += __shfl_xor(ssum, off);
    outI[b * 64 + t] = (float)idx;
    outS[b * 64 + t] = sv / (ssum + 1e-12f);
  }
}

// ---------------------------------------------------------------------------
// Host launcher.  Workspace (floats), U = 16,777,216:
//   h [0,U) | obuf [U,2U) | carea [2U,3.5U)  -- peak 3.5U*4 B = 224 MiB.
// ---------------------------------------------------------------------------
extern "C" void kernel_launch(void* const* d_in, const int* in_sizes, int n_in,
                              void* d_out, int out_size, void* d_ws, size_t ws_size,
                              hipStream_t stream)
{
  (void)in_sizes; (void)n_in; (void)out_size; (void)ws_size;
  const float* x      = (const float*)d_in[0];
  const float* gumbel = (const float*)d_in[1];
  const float* emb_W  = (const float*)d_in[2];
  const float* emb_b  = (const float*)d_in[3];
  const float* Wq     = (const float*)d_in[4];
  const float* Wk     = (const float*)d_in[5];
  const float* Wv     = (const float*)d_in[6];
  const float* Wo     = (const float*)d_in[7];
  const float* ln1_g  = (const float*)d_in[8];
  const float* ln1_b  = (const float*)d_in[9];
  const float* ln2_g  = (const float*)d_in[10];
  const float* ln2_b  = (const float*)d_in[11];
  const float* ffn_W1 = (const float*)d_in[12];
  const float* ffn_b1 = (const float*)d_in[13];
  const float* ffn_W2 = (const float*)d_in[14];
  const float* ffn_b2 = (const float*)d_in[15];
  const float* sha_Wq = (const float*)d_in[16];
  const float* sha_Wk = (const float*)d_in[17];
  const float* aW1    = (const float*)d_in[18];
  const float* ab1    = (const float*)d_in[19];
  const float* aW2    = (const float*)d_in[20];
  const float* ab2    = (const float*)d_in[21];

  float* ws = (float*)d_ws;
  const size_t U = (size_t)BB * NN * DD;
  float* h     = ws;
  float* obuf  = ws + U;
  float* carea = ws + 2 * U;
  const size_t HC = U / 2;
  float* qc = carea;
  float* kc = carea + HC;
  float* vc = carea + 2 * HC;
  float* fbuf = carea;
  float* hmean  = carea;
  float* qvb    = carea + BB * DD;
  float* allocp = carea + 2 * BB * DD;
  float* wcopy  = allocp + (size_t)BB * NN;

  float* outW = (float*)d_out;
  float* outI = outW + (size_t)BB * NN;
  float* outS = outI + BB * KSEL;

  const dim3 blk(256);
  const int M = BB * NN;

  auto GEMM = [&](const float* A, int lda, const float* Bp, int ldb,
                  float* C, int ldc, const float* bias, const float* res,
                  int ldres, int Mm, int Nn, int Kk, int relu, int accum) {
    gemm128_kernel<<<dim3(Nn / 128, Mm / 128), blk, 0, stream>>>(
        A, lda, Bp, ldb, C, ldc, bias, res, ldres, Kk, relu, accum);
  };

  embed_kernel<<<dim3(M / 4), blk, 0, stream>>>(x, emb_W, emb_b, h);

  for (int i = 0; i < LL; ++i) {
    const float* wq  = Wq + (size_t)i * DD * DD;
    const float* wk  = Wk + (size_t)i * DD * DD;
    const float* wvp = Wv + (size_t)i * DD * DD;
    const float* wo  = Wo + (size_t)i * DD * DD;
    const float* w1  = ffn_W1 + (size_t)i * DD * DFF2;
    const float* b1  = ffn_b1 + (size_t)i * DFF2;
    const float* w2  = ffn_W2 + (size_t)i * DFF2 * DD;
    const float* b2  = ffn_b2 + (size_t)i * DD;

    for (int half = 0; half < 2; ++half) {
      const size_t roff = (size_t)half * (M / 2) * DD;
      const int Mc = M / 2;
      GEMM(h + roff, DD, wq,  DD, qc, DD, nullptr, nullptr, 0, Mc, DD, DD, 0, 0);
      GEMM(h + roff, DD, wk,  DD, kc, DD, nullptr, nullptr, 0, Mc, DD, DD, 0, 0);
      GEMM(h + roff, DD, wvp, DD, vc, DD, nullptr, nullptr, 0, Mc, DD, DD, 0, 0);
      // flat 2048-block grid; kernel decodes (b, hh, qt) XCD-aware
      attn_kernel<<<dim3((NN / 64) * HH * (BB / 2)), dim3(64), 0, stream>>>(
          qc, kc, vc, obuf + roff);
    }
    GEMM(obuf, DD, wo, DD, h, DD, nullptr, h, DD, M, DD, DD, 0, 0);
    ln_kernel<<<dim3(M / 4), blk, 0, stream>>>(h, h, ln1_g + i * DD, ln1_b + i * DD);

    for (int c = 0; c < 4; ++c) {
      GEMM(h, DD, w1 + c * 256, DFF2, obuf, 256, b1 + c * 256, nullptr, 0,
           M, 256, DD, 1, 0);
      GEMM(obuf, 256, w2 + (size_t)c * 256 * DD, DD, fbuf, DD,
           (c == 0) ? b2 : nullptr, (c == 0) ? h : nullptr, DD,
           M, DD, 256, 0, (c == 0) ? 0 : 1);
    }
    ln_kernel<<<dim3(M / 4), blk, 0, stream>>>(fbuf, h, ln2_g + i * DD, ln2_b + i * DD);
  }

  rowmean_kernel<<<dim3(BB), blk, 0, stream>>>(h, hmean);
  final_small_kernel<<<dim3(BB), blk, 0, stream>>>(hmean, sha_Wq, aW1, ab1, aW2, ab2, qvb, allocp);
  GEMM(h, DD, sha_Wk, DD, obuf, DD, nullptr, nullptr, 0, M, DD, DD, 0, 0);
  scores_kernel<<<dim3(BB), blk, 0, stream>>>(qvb, obuf, gumbel, outW, wcopy);
  topk_kernel<<<dim3(BB), blk, 0, stream>>>(wcopy, allocp, outI, outS);
}

// Round 8
// 11624.110 us; speedup vs baseline: 1.2977x; 1.0383x over previous
//
#include <hip/hip_runtime.h>
#include <math.h>

// Problem constants
#define BB   64
#define NN   1024
#define DIN  16
#define DD   256
#define HH   4
#define LL   3
#define DHH  64
#define DFF2 1024
#define KSEL 64

// ---------------------------------------------------------------------------
// Embedding: h[row, :] = x[row, :16] @ emb_W + emb_b.  4 rows per block.
// ---------------------------------------------------------------------------
__global__ __launch_bounds__(256) void embed_kernel(
    const float* __restrict__ x, const float* __restrict__ W,
    const float* __restrict__ bias, float* __restrict__ h)
{
  __shared__ float xs[4][DIN];
  const int t = threadIdx.x, w = t >> 6, lane = t & 63;
  const size_t row = (size_t)blockIdx.x * 4 + w;
  if (lane < DIN) xs[w][lane] = x[row * DIN + lane];
  __syncthreads();
#pragma unroll
  for (int j = 0; j < 4; ++j) {
    const int col = lane + j * 64;
    float acc = bias[col];
#pragma unroll
    for (int kk = 0; kk < DIN; ++kk) acc = fmaf(xs[w][kk], W[kk * DD + col], acc);
    h[row * DD + col] = acc;
  }
}

// ---------------------------------------------------------------------------
// fp32 GEMM: C[M,N] = A[M,K] @ B[K,N] (+bias)(+res)(relu)(accum)
// 128x128 tile, BK=8, single-buffer, 256 threads, 8x8 micro.
// A octets at stride-12 dwords (2-way ty-octet reads); B rotate-interleaved
// col-quads (2-way reads).  acc[8][8] lives in AGPRs (VGPR=52, no memory
// spill -- verified R7 counters).
// ---------------------------------------------------------------------------
__global__ __launch_bounds__(256) void gemm128_kernel(
    const float* __restrict__ A, int lda,
    const float* __restrict__ Bm, int ldb,
    float* C, int ldc,
    const float* __restrict__ bias,
    const float* res, int ldres,
    int Kk, int relu, int accum)
{
  __shared__ __align__(16) float As[8][192];
  __shared__ __align__(16) float Bs[8][132];
  const int t = threadIdx.x;
  const int tx = t & 15, ty = t >> 4;
  const size_t row0 = (size_t)blockIdx.y * 128;
  const size_t col0 = (size_t)blockIdx.x * 128;
  const int arow = t >> 1, aq = (t & 1) * 4;
  const int acol = 12 * (arow >> 3) + (arow & 7);  // stride-12 octet layout
  const int brow = t >> 5, bcq = t & 31;
  const int bp = ((bcq >> 1) | ((bcq & 1) << 4)) * 4;
  float acc[8][8] = {};
  const float* Aptr = A + (row0 + arow) * lda + aq;
  const float* Bptr = Bm + (size_t)brow * ldb + col0 + bcq * 4;
  for (int k0 = 0; k0 < Kk; k0 += 8) {
    const float4 av = *(const float4*)(Aptr + k0);
    const float4 bv = *(const float4*)(Bptr + (size_t)k0 * ldb);
    As[aq + 0][acol] = av.x; As[aq + 1][acol] = av.y;
    As[aq + 2][acol] = av.z; As[aq + 3][acol] = av.w;
    *(float4*)&Bs[brow][bp] = bv;
    __syncthreads();
#pragma unroll
    for (int kk = 0; kk < 8; ++kk) {
      const float4 x0 = *(const float4*)&As[kk][ty * 12];
      const float4 x1 = *(const float4*)&As[kk][ty * 12 + 4];
      const float4 y0 = *(const float4*)&Bs[kk][tx * 4];
      const float4 y1 = *(const float4*)&Bs[kk][tx * 4 + 64];
      const float aa[8] = {x0.x, x0.y, x0.z, x0.w, x1.x, x1.y, x1.z, x1.w};
      const float bb2[8] = {y0.x, y0.y, y0.z, y0.w, y1.x, y1.y, y1.z, y1.w};
#pragma unroll
      for (int i = 0; i < 8; ++i)
#pragma unroll
        for (int j = 0; j < 8; ++j)
          acc[i][j] = fmaf(aa[i], bb2[j], acc[i][j]);
    }
    __syncthreads();
  }
#pragma unroll
  for (int i = 0; i < 8; ++i) {
    const size_t r = row0 + ty * 8 + i;
    float* cp = C + r * (size_t)ldc + col0 + tx * 8;
    const float* rp = res ? res + r * (size_t)ldres + col0 + tx * 8 : nullptr;
#pragma unroll
    for (int j = 0; j < 8; ++j) {
      const size_t c = col0 + tx * 8 + j;
      float v = acc[i][j];
      if (bias) v += bias[c];
      if (rp)   v += rp[j];
      if (relu) v = fmaxf(v, 0.f);
      if (accum) v += cp[j];
      cp[j] = v;
    }
  }
}

// ---------------------------------------------------------------------------
// Flash attention v8.  ONE WAVE per (b, head, 64 q-rows); 8x8 micro (F/R=16).
// Change vs v7: NO cross-barrier register prefetch (R7 proof: kreg/vreg
// arrays spilled to scratch -- 990 MB/dispatch write traffic, VGPR capped at
// 132 addressable).  K/V staged per-phase with SHORT-LIVED 16xfloat4 temps
// (live only while S is dead) -> peak live ~175 regs, zero spill.  The two
// exposed ~300 cy L2 waits per k-tile cost ~4% -- the predictable trade.
// XCD-aware flat-grid decode kept (R7: FETCH 538->115 MB).
// LDS 52736 B -> 3 single-wave blocks/CU.
// ---------------------------------------------------------------------------
__global__ __launch_bounds__(64, 1) void attn_kernel(
    const float* __restrict__ qb, const float* __restrict__ kb,
    const float* __restrict__ vb, float* __restrict__ ob)
{
  __shared__ __align__(16) float Qn[64 * 68];
  __shared__ __align__(16) float KV[64 * 68];
  __shared__ __align__(16) float Pt[64 * 68];
  __shared__ float alphaL[64];
  __shared__ float lrunL[64];
  const int t = threadIdx.x;
  const int A = t >> 3, Bd = t & 7;
  // XCD-aware decode: f mod 32 == batch -> f mod 8 == b mod 8 (fixed XCD)
  const int f = blockIdx.x;
  const int b = f & 31;
  const int rest = f >> 5;
  const int qt = rest & 15, hh = rest >> 4;
  const size_t base = ((size_t)b * NN) * DD + (size_t)hh * DHH;
  const int srow = t >> 4, scq = t & 15;  // staging: rows srow+4u, quad scq

  // ---- stage Q + K0 ----
  {
    const float* qp = qb + base + (size_t)(qt * 64) * DD + scq * 4;
    const float* kp = kb + base + scq * 4;
#pragma unroll
    for (int u = 0; u < 16; ++u) {
      const int r = srow + 4 * u;
      *(float4*)&Qn[r * 68 + scq * 4] = *(const float4*)(qp + (size_t)r * DD);
      *(float4*)&KV[r * 68 + scq * 4] = *(const float4*)(kp + (size_t)r * DD);
    }
  }
  lrunL[t] = 0.f;
  float mrun[8];
#pragma unroll
  for (int i = 0; i < 8; ++i) mrun[i] = -1e30f;
  float O[8][8] = {};
  __syncthreads();

  for (int kt = 0; kt < 16; ++kt) {
    // ---- S = Q K^T (rows A+8i, cols Bd+8j) ----
    float S[8][8];
#pragma unroll
    for (int i = 0; i < 8; ++i)
#pragma unroll
      for (int j = 0; j < 8; ++j) S[i][j] = 0.f;
#pragma unroll 2
    for (int dq = 0; dq < 16; ++dq) {
      float4 k4[8];
#pragma unroll
      for (int j = 0; j < 8; ++j)
        k4[j] = *(const float4*)&KV[(Bd + 8 * j) * 68 + dq * 4];
#pragma unroll
      for (int i = 0; i < 8; ++i) {
        const float4 q4 = *(const float4*)&Qn[(A + 8 * i) * 68 + dq * 4];
#pragma unroll
        for (int j = 0; j < 8; ++j)
          S[i][j] += q4.x * k4[j].x + q4.y * k4[j].y +
                     q4.z * k4[j].z + q4.w * k4[j].w;
      }
    }

    // ---- online softmax per q-row (8 local cols x 8 Bd lanes) ----
#pragma unroll
    for (int i = 0; i < 8; ++i) {
      float mt = -1e30f;
#pragma unroll
      for (int j = 0; j < 8; ++j) { S[i][j] *= 0.125f; mt = fmaxf(mt, S[i][j]); }
      mt = fmaxf(mt, __shfl_xor(mt, 1));
      mt = fmaxf(mt, __shfl_xor(mt, 2));
      mt = fmaxf(mt, __shfl_xor(mt, 4));
      const float mnew = fmaxf(mrun[i], mt);
      const float alpha = __expf(mrun[i] - mnew);
      mrun[i] = mnew;
      float rs = 0.f;
#pragma unroll
      for (int j = 0; j < 8; ++j) { S[i][j] = __expf(S[i][j] - mnew); rs += S[i][j]; }
      rs += __shfl_xor(rs, 1);
      rs += __shfl_xor(rs, 2);
      rs += __shfl_xor(rs, 4);
      if (Bd == 0) {
        alphaL[A + 8 * i] = alpha;
        lrunL[A + 8 * i] = lrunL[A + 8 * i] * alpha + rs;
      }
      // P^T scatter: Pt[c = Bd+8j][q = A+8i]
#pragma unroll
      for (int j = 0; j < 8; ++j)
        Pt[(Bd + 8 * j) * 68 + (A + 8 * i)] = S[i][j];
    }
    __syncthreads();  // bar A: K reads done; Pt/alpha visible

    // ---- stage V_kt into KV (short-lived temps; S is dead here) ----
    {
      const float* vp = vb + base + (size_t)(kt * 64) * DD + scq * 4;
      float4 tmp[16];
#pragma unroll
      for (int u = 0; u < 16; ++u)
        tmp[u] = *(const float4*)(vp + (size_t)(srow + 4 * u) * DD);
#pragma unroll
      for (int u = 0; u < 16; ++u)
        *(float4*)&KV[(srow + 4 * u) * 68 + scq * 4] = tmp[u];
    }
    __syncthreads();  // bar B: V visible

    // ---- O = O*alpha + P V (rows 8A+i, cols 8Bd+j) ----
#pragma unroll
    for (int i = 0; i < 8; ++i) {
      const float al = alphaL[8 * A + i];
#pragma unroll
      for (int j = 0; j < 8; ++j) O[i][j] *= al;
    }
#pragma unroll 4
    for (int c = 0; c < 64; ++c) {
      const float4 p0 = *(const float4*)&Pt[c * 68 + 8 * A];
      const float4 p1 = *(const float4*)&Pt[c * 68 + 8 * A + 4];
      const float4 v0 = *(const float4*)&KV[c * 68 + 8 * Bd];
      const float4 v1 = *(const float4*)&KV[c * 68 + 8 * Bd + 4];
      const float pp[8] = {p0.x, p0.y, p0.z, p0.w, p1.x, p1.y, p1.z, p1.w};
      const float vv[8] = {v0.x, v0.y, v0.z, v0.w, v1.x, v1.y, v1.z, v1.w};
#pragma unroll
      for (int i = 0; i < 8; ++i)
#pragma unroll
        for (int j = 0; j < 8; ++j)
          O[i][j] = fmaf(pp[i], vv[j], O[i][j]);
    }
    __syncthreads();  // bar C: V reads done

    // ---- stage K_{kt+1} into KV (short-lived temps) ----
    {
      const float* kp = kb + base + (size_t)(((kt + 1) & 15) * 64) * DD + scq * 4;
      float4 tmp[16];
#pragma unroll
      for (int u = 0; u < 16; ++u)
        tmp[u] = *(const float4*)(kp + (size_t)(srow + 4 * u) * DD);
#pragma unroll
      for (int u = 0; u < 16; ++u)
        *(float4*)&KV[(srow + 4 * u) * 68 + scq * 4] = tmp[u];
    }
    __syncthreads();  // bar D: K visible
  }

  // ---- write O (rows 8A+i, d-cols 8Bd..8Bd+7) ----
#pragma unroll
  for (int i = 0; i < 8; ++i) {
    const int r = 8 * A + i;
    const float inv = 1.f / lrunL[r];
    const float4 o0 = {O[i][0] * inv, O[i][1] * inv, O[i][2] * inv, O[i][3] * inv};
    const float4 o1 = {O[i][4] * inv, O[i][5] * inv, O[i][6] * inv, O[i][7] * inv};
    float* op = ob + base + (size_t)(qt * 64 + r) * DD + 8 * Bd;
    *(float4*)op = o0;
    *(float4*)(op + 4) = o1;
  }
}

// ---------------------------------------------------------------------------
// LayerNorm over D=256, 4 rows/block (one wave per row, shfl reduce).
// ---------------------------------------------------------------------------
__global__ __launch_bounds__(256) void ln_kernel(
    const float* in, float* out,
    const float* __restrict__ g, const float* __restrict__ bb)
{
  const int t = threadIdx.x, w = t >> 6, lane = t & 63;
  const size_t row = (size_t)blockIdx.x * 4 + w;
  const float4 val = *(const float4*)(in + row * DD + lane * 4);
  float s = val.x + val.y + val.z + val.w;
#pragma unroll
  for (int off = 32; off; off >>= 1) s += __shfl_xor(s, off);
  const float mean = s * (1.f / 256.f);
  const float dx = val.x - mean, dy = val.y - mean, dz = val.z - mean, dw = val.w - mean;
  float ss = dx * dx + dy * dy + dz * dz + dw * dw;
#pragma unroll
  for (int off = 32; off; off >>= 1) ss += __shfl_xor(ss, off);
  const float inv = rsqrtf(ss * (1.f / 256.f) + 1e-5f);
  const float4 g4 = *(const float4*)(g + lane * 4);
  const float4 b4 = *(const float4*)(bb + lane * 4);
  float4 o4;
  o4.x = dx * inv * g4.x + b4.x;
  o4.y = dy * inv * g4.y + b4.y;
  o4.z = dz * inv * g4.z + b4.z;
  o4.w = dw * inv * g4.w + b4.w;
  *(float4*)(out + row * DD + lane * 4) = o4;
}

// ---------------------------------------------------------------------------
// h_mean[b, :] = mean over N of h[b, :, :]
// ---------------------------------------------------------------------------
__global__ __launch_bounds__(256) void rowmean_kernel(
    const float* __restrict__ h, float* __restrict__ hm)
{
  const int t = threadIdx.x, b = blockIdx.x;
  const float* p = h + (size_t)b * NN * DD + t;
  float acc = 0.f;
  for (int n = 0; n < NN; ++n) acc += p[(size_t)n * DD];
  hm[b * DD + t] = acc * (1.f / NN);
}

// ---------------------------------------------------------------------------
// Per-batch small heads: qv = h_mean@sha_Wq; alloc = softmax(relu(h_mean@W1+b1)@W2+b2)
// ---------------------------------------------------------------------------
__global__ __launch_bounds__(256) void final_small_kernel(
    const float* __restrict__ hm, const float* __restrict__ shaWq,
    const float* __restrict__ W1, const float* __restrict__ b1,
    const float* __restrict__ W2, const float* __restrict__ b2,
    float* __restrict__ qv, float* __restrict__ allocp)
{
  __shared__ float hs[256];
  __shared__ float mids[256];
  __shared__ float red[256];
  const int t = threadIdx.x, b = blockIdx.x;
  hs[t] = hm[b * 256 + t];
  __syncthreads();
  float a = 0.f, m2 = b1[t];
  for (int kk = 0; kk < 256; ++kk) {
    const float hv = hs[kk];
    a  = fmaf(hv, shaWq[kk * 256 + t], a);
    m2 = fmaf(hv, W1[kk * 256 + t], m2);
  }
  qv[b * 256 + t] = a;
  mids[t] = fmaxf(m2, 0.f);
  __syncthreads();
  float lg[4];
#pragma unroll
  for (int j = 0; j < 4; ++j) {
    const int n = t + j * 256;
    float acc2 = b2[n];
    for (int kk = 0; kk < 256; ++kk) acc2 = fmaf(mids[kk], W2[kk * 1024 + n], acc2);
    lg[j] = acc2;
  }
  float m = fmaxf(fmaxf(lg[0], lg[1]), fmaxf(lg[2], lg[3]));
  red[t] = m; __syncthreads();
  for (int s2 = 128; s2; s2 >>= 1) { if (t < s2) red[t] = fmaxf(red[t], red[t + s2]); __syncthreads(); }
  m = red[0]; __syncthreads();
  float e[4]; float ls = 0.f;
#pragma unroll
  for (int j = 0; j < 4; ++j) { e[j] = expf(lg[j] - m); ls += e[j]; }
  red[t] = ls; __syncthreads();
  for (int s2 = 128; s2; s2 >>= 1) { if (t < s2) red[t] += red[t + s2]; __syncthreads(); }
  const float invs = 1.f / red[0];
#pragma unroll
  for (int j = 0; j < 4; ++j) allocp[(size_t)b * 1024 + t + j * 256] = e[j] * invs;
}

// ---------------------------------------------------------------------------
// scores[b,n] = dot(qv[b], kv[b,n])/16; weights = softmax((scores+g)/0.5)
// ---------------------------------------------------------------------------
__global__ __launch_bounds__(256) void scores_kernel(
    const float* __restrict__ qv, const float* __restrict__ kv,
    const float* __restrict__ gum, float* __restrict__ outW,
    float* __restrict__ wcopy)
{
  __shared__ __align__(16) float qs[256];
  __shared__ float sc[1024];
  __shared__ float red[256];
  const int t = threadIdx.x, b = blockIdx.x;
  const int w = t >> 6, lane = t & 63;
  qs[t] = qv[b * 256 + t];
  __syncthreads();
  const float4 myq = *(const float4*)&qs[lane * 4];
  for (int n = w; n < 1024; n += 4) {
    const float4 k4 = *(const float4*)(kv + ((size_t)b * 1024 + n) * 256 + lane * 4);
    float d = myq.x * k4.x + myq.y * k4.y + myq.z * k4.z + myq.w * k4.w;
#pragma unroll
    for (int off = 32; off; off >>= 1) d += __shfl_xor(d, off);
    if (lane == 0) sc[n] = d * (1.f / 16.f);
  }
  __syncthreads();
  float z[4];
#pragma unroll
  for (int j = 0; j < 4; ++j) {
    const int n = t + j * 256;
    z[j] = (sc[n] + gum[(size_t)b * 1024 + n]) * 2.0f;  // /TAU, TAU=0.5
  }
  float m = fmaxf(fmaxf(z[0], z[1]), fmaxf(z[2], z[3]));
  red[t] = m; __syncthreads();
  for (int s2 = 128; s2; s2 >>= 1) { if (t < s2) red[t] = fmaxf(red[t], red[t + s2]); __syncthreads(); }
  m = red[0]; __syncthreads();
  float e[4]; float ls = 0.f;
#pragma unroll
  for (int j = 0; j < 4; ++j) { e[j] = expf(z[j] - m); ls += e[j]; }
  red[t] = ls; __syncthreads();
  for (int s2 = 128; s2; s2 >>= 1) { if (t < s2) red[t] += red[t + s2]; __syncthreads(); }
  const float invs = 1.f / red[0];
#pragma unroll
  for (int j = 0; j < 4; ++j) {
    const int n = t + j * 256;
    const float wv = e[j] * invs;
    outW[(size_t)b * 1024 + n] = wv;
    wcopy[(size_t)b * 1024 + n] = wv;
  }
}

// ---------------------------------------------------------------------------
// Top-64 (descending, ties -> lower index, matching jax.lax.top_k) + sel gather.
// ---------------------------------------------------------------------------
__global__ __launch_bounds__(256) void topk_kernel(
    const float* __restrict__ wcopy, const float* __restrict__ allocp,
    float* __restrict__ outI, float* __restrict__ outS)
{
  __shared__ float wv[1024];
  __shared__ float rv[4];
  __shared__ int   ri[4];
  __shared__ int   sel[64];
  const int t = threadIdx.x, b = blockIdx.x;
  const int w = t >> 6, lane = t & 63;
#pragma unroll
  for (int j = 0; j < 4; ++j) wv[t * 4 + j] = wcopy[(size_t)b * 1024 + t * 4 + j];
  __syncthreads();
  for (int it = 0; it < 64; ++it) {
    float bv = -1.f; int bi = 1 << 20;
#pragma unroll
    for (int j = 0; j < 4; ++j) {
      const int n = t * 4 + j;
      const float v2 = wv[n];
      if (v2 > bv || (v2 == bv && n < bi)) { bv = v2; bi = n; }
    }
#pragma unroll
    for (int off = 32; off; off >>= 1) {
      const float ov = __shfl_xor(bv, off);
      const int   oi = __shfl_xor(bi, off);
      if (ov > bv || (ov == bv && oi < bi)) { bv = ov; bi = oi; }
    }
    if (lane == 0) { rv[w] = bv; ri[w] = bi; }
    __syncthreads();
    if (t == 0) {
      float B2 = rv[0]; int I2 = ri[0];
      for (int u = 1; u < 4; ++u)
        if (rv[u] > B2 || (rv[u] == B2 && ri[u] < I2)) { B2 = rv[u]; I2 = ri[u]; }
      sel[it] = I2;
      wv[I2] = -1.f;
    }
    __syncthreads();
  }
  if (t < 64) {
    const int idx = sel[t];
    const float sv = allocp[(size_t)b * 1024 + idx];
    float ssum = sv;
#pragma unroll
    for (int off = 32; off; off >>= 1) ssum += __shfl_xor(ssum, off);
    outI[b * 64 + t] = (float)idx;
    outS[b * 64 + t] = sv / (ssum + 1e-12f);
  }
}

// ---------------------------------------------------------------------------
// Host launcher.  Workspace (floats), U = 16,777,216:
//   h [0,U) | obuf [U,2U) | carea [2U,3.5U)  -- peak 3.5U*4 B = 224 MiB.
// ---------------------------------------------------------------------------
extern "C" void kernel_launch(void* const* d_in, const int* in_sizes, int n_in,
                              void* d_out, int out_size, void* d_ws, size_t ws_size,
                              hipStream_t stream)
{
  (void)in_sizes; (void)n_in; (void)out_size; (void)ws_size;
  const float* x      = (const float*)d_in[0];
  const float* gumbel = (const float*)d_in[1];
  const float* emb_W  = (const float*)d_in[2];
  const float* emb_b  = (const float*)d_in[3];
  const float* Wq     = (const float*)d_in[4];
  const float* Wk     = (const float*)d_in[5];
  const float* Wv     = (const float*)d_in[6];
  const float* Wo     = (const float*)d_in[7];
  const float* ln1_g  = (const float*)d_in[8];
  const float* ln1_b  = (const float*)d_in[9];
  const float* ln2_g  = (const float*)d_in[10];
  const float* ln2_b  = (const float*)d_in[11];
  const float* ffn_W1 = (const float*)d_in[12];
  const float* ffn_b1 = (const float*)d_in[13];
  const float* ffn_W2 = (const float*)d_in[14];
  const float* ffn_b2 = (const float*)d_in[15];
  const float* sha_Wq = (const float*)d_in[16];
  const float* sha_Wk = (const float*)d_in[17];
  const float* aW1    = (const float*)d_in[18];
  const float* ab1    = (const float*)d_in[19];
  const float* aW2    = (const float*)d_in[20];
  const float* ab2    = (const float*)d_in[21];

  float* ws = (float*)d_ws;
  const size_t U = (size_t)BB * NN * DD;
  float* h     = ws;
  float* obuf  = ws + U;
  float* carea = ws + 2 * U;
  const size_t HC = U / 2;
  float* qc = carea;
  float* kc = carea + HC;
  float* vc = carea + 2 * HC;
  float* fbuf = carea;
  float* hmean  = carea;
  float* qvb    = carea + BB * DD;
  float* allocp = carea + 2 * BB * DD;
  float* wcopy  = allocp + (size_t)BB * NN;

  float* outW = (float*)d_out;
  float* outI = outW + (size_t)BB * NN;
  float* outS = outI + BB * KSEL;

  const dim3 blk(256);
  const int M = BB * NN;

  auto GEMM = [&](const float* A, int lda, const float* Bp, int ldb,
                  float* C, int ldc, const float* bias, const float* res,
                  int ldres, int Mm, int Nn, int Kk, int relu, int accum) {
    gemm128_kernel<<<dim3(Nn / 128, Mm / 128), blk, 0, stream>>>(
        A, lda, Bp, ldb, C, ldc, bias, res, ldres, Kk, relu, accum);
  };

  embed_kernel<<<dim3(M / 4), blk, 0, stream>>>(x, emb_W, emb_b, h);

  for (int i = 0; i < LL; ++i) {
    const float* wq  = Wq + (size_t)i * DD * DD;
    const float* wk  = Wk + (size_t)i * DD * DD;
    const float* wvp = Wv + (size_t)i * DD * DD;
    const float* wo  = Wo + (size_t)i * DD * DD;
    const float* w1  = ffn_W1 + (size_t)i * DD * DFF2;
    const float* b1  = ffn_b1 + (size_t)i * DFF2;
    const float* w2  = ffn_W2 + (size_t)i * DFF2 * DD;
    const float* b2  = ffn_b2 + (size_t)i * DD;

    for (int half = 0; half < 2; ++half) {
      const size_t roff = (size_t)half * (M / 2) * DD;
      const int Mc = M / 2;
      GEMM(h + roff, DD, wq,  DD, qc, DD, nullptr, nullptr, 0, Mc, DD, DD, 0, 0);
      GEMM(h + roff, DD, wk,  DD, kc, DD, nullptr, nullptr, 0, Mc, DD, DD, 0, 0);
      GEMM(h + roff, DD, wvp, DD, vc, DD, nullptr, nullptr, 0, Mc, DD, DD, 0, 0);
      attn_kernel<<<dim3((NN / 64) * HH * (BB / 2)), dim3(64), 0, stream>>>(
          qc, kc, vc, obuf + roff);
    }
    GEMM(obuf, DD, wo, DD, h, DD, nullptr, h, DD, M, DD, DD, 0, 0);
    ln_kernel<<<dim3(M / 4), blk, 0, stream>>>(h, h, ln1_g + i * DD, ln1_b + i * DD);

    for (int c = 0; c < 4; ++c) {
      GEMM(h, DD, w1 + c * 256, DFF2, obuf, 256, b1 + c * 256, nullptr, 0,
           M, 256, DD, 1, 0);
      GEMM(obuf, 256, w2 + (size_t)c * 256 * DD, DD, fbuf, DD,
           (c == 0) ? b2 : nullptr, (c == 0) ? h : nullptr, DD,
           M, DD, 256, 0, (c == 0) ? 0 : 1);
    }
    ln_kernel<<<dim3(M / 4), blk, 0, stream>>>(fbuf, h, ln2_g + i * DD, ln2_b + i * DD);
  }

  rowmean_kernel<<<dim3(BB), blk, 0, stream>>>(h, hmean);
  final_small_kernel<<<dim3(BB), blk, 0, stream>>>(hmean, sha_Wq, aW1, ab1, aW2, ab2, qvb, allocp);
  GEMM(h, DD, sha_Wk, DD, obuf, DD, nullptr, nullptr, 0, M, DD, DD, 0, 0);
  scores_kernel<<<dim3(BB), blk, 0, stream>>>(qvb, obuf, gumbel, outW, wcopy);
  topk_kernel<<<dim3(BB), blk, 0, stream>>>(wcopy, allocp, outI, outS);
}